// Round 5
// baseline (849.528 us; speedup 1.0000x reference)
//
#include <hip/hip_runtime.h>
#include <cstdint>
#include <cstddef>

// Problem constants
#define N0c 30000
#define F0c 128
#define Hc  256
#define Cc  16
#define N1c 3000
#define Bc  16
#define E0c 960000
#define E1c 48000
#define EPSc 1e-5f

// Padded row strides (floats) to break L2 channel camping:
// 256-wide rows: 264 floats = 1056B (not a multiple of 1024 -> segment class
// of chunk*128 varies per row). 128-wide rows: 136 floats = 544B.
#define LD256 264
#define LD256v4 66
#define LD128 136
#define LD128v4 34

static __host__ __device__ inline int cdiv_i(int a, int b) { return (a + b - 1) / b; }

// ---------------- graph preprocessing ----------------

__global__ void count_deg(const int* __restrict__ dst, int E, int* __restrict__ deg) {
    int e = blockIdx.x * blockDim.x + threadIdx.x;
    if (e < E) atomicAdd(&deg[dst[e]], 1);
}

__global__ void calc_dinv(const int* __restrict__ deg, float* __restrict__ dinv, int n) {
    int i = blockIdx.x * blockDim.x + threadIdx.x;
    if (i < n) dinv[i] = rsqrtf((float)(deg[i] + 1));  // +1 self loop, always > 0
}

// exclusive scan of cnt[n] -> rp[n] (+ rp[n]=total), 3-kernel multi-block scan (nb<=256)
__global__ void scan_block(const int* __restrict__ cnt, int n, int* __restrict__ rp,
                           int* __restrict__ blkSum) {
    __shared__ int sh[256];
    int t = threadIdx.x;
    int i = blockIdx.x * 256 + t;
    int v = (i < n) ? cnt[i] : 0;
    sh[t] = v; __syncthreads();
    for (int off = 1; off < 256; off <<= 1) {
        int add = (t >= off) ? sh[t - off] : 0;
        __syncthreads();
        sh[t] += add;
        __syncthreads();
    }
    if (i < n) rp[i] = sh[t] - v;
    if (t == 255) blkSum[blockIdx.x] = sh[255];
}

__global__ void scan_sums(const int* __restrict__ blkSum, int nb, int* __restrict__ blkOff,
                          int* __restrict__ rp, int n) {
    __shared__ int sh[256];
    int t = threadIdx.x;
    int v = (t < nb) ? blkSum[t] : 0;
    sh[t] = v; __syncthreads();
    for (int off = 1; off < 256; off <<= 1) {
        int add = (t >= off) ? sh[t - off] : 0;
        __syncthreads();
        sh[t] += add;
        __syncthreads();
    }
    blkOff[t] = sh[t] - v;
    if (t == 255) rp[n] = sh[255];
}

__global__ void scan_add(int* __restrict__ rp, int n, const int* __restrict__ blkOff) {
    int i = blockIdx.x * 256 + threadIdx.x;
    if (i < n) rp[i] += blkOff[blockIdx.x];
}

// packed CSR entry: {src, float_bits(weight)} -> one 8B load per edge
__global__ void fill_csr(const int* __restrict__ src, const int* __restrict__ dst, int E,
                         const int* __restrict__ rp, int* __restrict__ tmp,
                         const float* __restrict__ dinv, int2* __restrict__ csw) {
    int e = blockIdx.x * blockDim.x + threadIdx.x;
    if (e >= E) return;
    int s = src[e], d = dst[e];
    int pos = rp[d] + atomicAdd(&tmp[d], 1);
    int2 v;
    v.x = s;
    v.y = __float_as_int(dinv[s] * dinv[d]);
    csw[pos] = v;
}

// copy x (30000 x 128, compact) into padded layout (stride LD128)
__global__ void pad_x128(const float* __restrict__ x, float* __restrict__ xp) {
    int i = blockIdx.x * 256 + threadIdx.x;  // float4 index
    if (i >= N0c * 32) return;
    int node = i >> 5, c = i & 31;
    ((float4*)xp)[(size_t)node * LD128v4 + c] = ((const float4*)x)[i];
}

// ---------------- aggregation ----------------

// Wide column-split aggregation, software-pipelined, PADDED row stride.
// RS4 = row stride in float4 units (66 for 256-wide, 34 for 128-wide).
// NCHUNK chunks of 32 cols; chunk = blockIdx & (NCHUNK-1) pins each chunk to a
// fixed XCD set (round-robin dispatch) -> per-XCD gather slice fits in 4MB L2.
// Padded stride (non-multiple of 1024B) makes the 128B-segment class of each
// chunk's gathers vary with row index -> spreads L2 channels (de-camping).
// Block = 256 threads = 4 waves; each wave handles one node.
// lane = par*8+cl; par picks edge slot, cl picks float4 in chunk. Edge
// metadata batch-loaded 64-per-instruction, distributed via __shfl.
template <int RS4, int NCHUNK>
__global__ __launch_bounds__(256) void agg_wide(
    const float* __restrict__ x, const int* __restrict__ rp,
    const int2* __restrict__ csw, const float* __restrict__ dinv,
    float* __restrict__ z, int N) {
    int b = blockIdx.x;
    int chunk = b & (NCHUNK - 1);
    int wave = threadIdx.x >> 6;
    int node = (b / NCHUNK) * 4 + wave;
    if (node >= N) return;
    int lane = threadIdx.x & 63;
    int par = lane >> 3;      // 0..7 edge slot
    int cl = lane & 7;        // float4 lane within 32-col chunk
    int c4 = chunk * 8 + cl;  // float4 column index
    const float4* x4 = (const float4*)x;
    float4 a = make_float4(0.f, 0.f, 0.f, 0.f);
    if (par == 0) {  // self-loop term exactly once
        float di = dinv[node];
        float w0 = di * di;
        float4 xv = x4[(size_t)node * RS4 + c4];
        a.x = w0 * xv.x; a.y = w0 * xv.y; a.z = w0 * xv.z; a.w = w0 * xv.w;
    }
    int e0 = rp[node], e1 = rp[node + 1];
    for (int base = e0; base < e1; base += 64) {
        int avail = e1 - base;               // may exceed 64
        int2 my = make_int2(0, 0);
        if (lane < avail) my = csw[base + lane];  // 64 edges in ONE load
        int cnt = avail < 64 ? avail : 64;
#pragma unroll
        for (int i = 0; i < 8; ++i) {
            int idx = i * 8 + par;
            int sx = __shfl(my.x, idx, 64);
            float w = __int_as_float(__shfl(my.y, idx, 64));
            if (idx < cnt) {
                float4 v = x4[(size_t)sx * RS4 + c4];
                a.x += w * v.x; a.y += w * v.y; a.z += w * v.z; a.w += w * v.w;
            }
        }
    }
#pragma unroll
    for (int m = 8; m < 64; m <<= 1) {
        a.x += __shfl_xor(a.x, m, 64);
        a.y += __shfl_xor(a.y, m, 64);
        a.z += __shfl_xor(a.z, m, 64);
        a.w += __shfl_xor(a.w, m, 64);
    }
    if (par == 0) ((float4*)z)[(size_t)node * RS4 + c4] = a;
}

// small F (17), scalar, compact strides
__global__ void agg_small(const float* __restrict__ x, const int* __restrict__ rp,
                          const int2* __restrict__ csw, const float* __restrict__ dinv,
                          float* __restrict__ z, int F) {
    int node = blockIdx.x;
    int t = threadIdx.x;
    if (t >= F) return;
    float di = dinv[node];
    float acc = di * di * x[(size_t)node * F + t];
    int e0 = rp[node], e1 = rp[node + 1];
    for (int e = e0; e < e1; ++e) {
        int2 sw = csw[e];
        acc += __int_as_float(sw.y) * x[(size_t)sw.x * F + t];
    }
    z[(size_t)node * F + t] = acc;
}

// ---------------- GEMM (M x K) @ (K x 256) + bias + BN (+ReLU) ----------------
// 64x64 tile, 256 threads, 4x4 microtile, BK=16. A and out use lda/ldc strides.

template <int K, bool RELU, bool ZEROEMPTY>
__global__ __launch_bounds__(256) void gemm_bn(
    const float* __restrict__ A, const float* __restrict__ W,
    const float* __restrict__ bias, const float* __restrict__ gam,
    const float* __restrict__ bet, const float* __restrict__ mu,
    const float* __restrict__ var, const int* __restrict__ cnt,
    float* __restrict__ out, int M, int lda, int ldc) {
    __shared__ __align__(16) float As[16][64];
    __shared__ __align__(16) float Bs[16][64];
    int tid = threadIdx.x;
    int tm = tid >> 4, tn = tid & 15;
    int row0 = blockIdx.x * 64, col0 = blockIdx.y * 64;
    float acc[4][4] = {};
    int ar = tid >> 2;           // 0..63
    int ak = (tid & 3) * 4;      // 0,4,8,12
    int bk = tid >> 4;           // 0..15
    int bn = (tid & 15) * 4;     // 0..60

    for (int kk = 0; kk < K; kk += 16) {
        float4 av = make_float4(0.f, 0.f, 0.f, 0.f);
        int grow = row0 + ar;
        if (grow < M) av = *(const float4*)(A + (size_t)grow * lda + kk + ak);
        As[ak + 0][ar] = av.x;
        As[ak + 1][ar] = av.y;
        As[ak + 2][ar] = av.z;
        As[ak + 3][ar] = av.w;
        float4 bv = *(const float4*)(W + (size_t)(kk + bk) * 256 + col0 + bn);
        *(float4*)&Bs[bk][bn] = bv;
        __syncthreads();
#pragma unroll
        for (int k = 0; k < 16; ++k) {
            float4 a = *(const float4*)&As[k][tm * 4];
            float4 b = *(const float4*)&Bs[k][tn * 4];
            acc[0][0] += a.x * b.x; acc[0][1] += a.x * b.y; acc[0][2] += a.x * b.z; acc[0][3] += a.x * b.w;
            acc[1][0] += a.y * b.x; acc[1][1] += a.y * b.y; acc[1][2] += a.y * b.z; acc[1][3] += a.y * b.w;
            acc[2][0] += a.z * b.x; acc[2][1] += a.z * b.y; acc[2][2] += a.z * b.z; acc[2][3] += a.z * b.w;
            acc[3][0] += a.w * b.x; acc[3][1] += a.w * b.y; acc[3][2] += a.w * b.z; acc[3][3] += a.w * b.w;
        }
        __syncthreads();
    }
    // epilogue: per-column BN params
    float bcol[4], scol[4], mcol[4], ecol[4];
#pragma unroll
    for (int j = 0; j < 4; ++j) {
        int col = col0 + tn * 4 + j;
        bcol[j] = bias[col];
        scol[j] = gam[col] * rsqrtf(var[col] + EPSc);
        mcol[j] = mu[col];
        ecol[j] = bet[col];
    }
#pragma unroll
    for (int i = 0; i < 4; ++i) {
        int row = row0 + tm * 4 + i;
        if (row >= M) continue;
        bool zero = false;
        if (ZEROEMPTY) zero = (cnt[row] == 0);
        float4 o;
        float r[4];
#pragma unroll
        for (int j = 0; j < 4; ++j) {
            float v = acc[i][j] + bcol[j];
            v = (v - mcol[j]) * scol[j] + ecol[j];
            if (RELU) v = fmaxf(v, 0.f);
            if (zero) v = 0.f;
            r[j] = v;
        }
        o.x = r[0]; o.y = r[1]; o.z = r[2]; o.w = r[3];
        *(float4*)(out + (size_t)row * ldc + col0 + tn * 4) = o;
    }
}

// K=17 GEMM: block per row, 256 threads; out padded stride LD256
__global__ void gemm17_bn_relu(const float* __restrict__ A, const float* __restrict__ W,
                               const float* __restrict__ bias, const float* __restrict__ gam,
                               const float* __restrict__ bet, const float* __restrict__ mu,
                               const float* __restrict__ var, float* __restrict__ out) {
    int r = blockIdx.x, t = threadIdx.x;
    __shared__ float zr[17];
    if (t < 17) zr[t] = A[(size_t)r * 17 + t];
    __syncthreads();
    float acc = bias[t];
#pragma unroll
    for (int k = 0; k < 17; ++k) acc += zr[k] * W[k * 256 + t];
    float s = gam[t] * rsqrtf(var[t] + EPSc);
    acc = (acc - mu[t]) * s + bet[t];
    acc = fmaxf(acc, 0.f);
    out[(size_t)r * LD256 + t] = acc;
}

// ---------------- pooling ----------------

// cluster starts from SORTED pool1
__global__ void seg_starts(const int* __restrict__ pool, int n, int nseg,
                           int* __restrict__ start) {
    int i = blockIdx.x * blockDim.x + threadIdx.x;
    if (i > n) return;
    if (i == 0) {
        for (int c = 0; c <= pool[0]; ++c) start[c] = 0;
    } else if (i == n) {
        for (int c = pool[n - 1] + 1; c <= nseg; ++c) start[c] = n;
    } else {
        int a = pool[i - 1], b = pool[i];
        for (int c = a + 1; c <= b; ++c) start[c] = i;
    }
}

// block per cluster: mean of z rows (padded stride) + cnt + bpool
__global__ void pool_mean(const float* __restrict__ z, const int* __restrict__ start,
                          const int* __restrict__ batch, float* __restrict__ p,
                          int* __restrict__ cnt_out, int* __restrict__ bpool) {
    int c = blockIdx.x, t = threadIdx.x;  // 64 threads
    int s = start[c], e = start[c + 1];
    int cnt = e - s;
    const float4* z4 = (const float4*)z;
    float ax = 0.f, ay = 0.f, az = 0.f, aw = 0.f;
    for (int i = s; i < e; ++i) {
        float4 v = z4[(size_t)i * LD256v4 + t];
        ax += v.x; ay += v.y; az += v.z; aw += v.w;
    }
    float inv = 1.0f / (float)max(cnt, 1);
    float4 o; o.x = ax * inv; o.y = ay * inv; o.z = az * inv; o.w = aw * inv;
    ((float4*)p)[(size_t)c * LD256v4 + t] = o;
    if (t == 0) {
        cnt_out[c] = cnt;
        int sb = 0;
        for (int i = s; i < e; ++i) sb += batch[i];
        bpool[c] = (int)rintf((float)sb * inv);  // exact integer -> round safe
    }
}

__global__ void pool_b_accum(const float* __restrict__ z, const int* __restrict__ bpool,
                             float* __restrict__ pb) {
    int c = blockIdx.x, t = threadIdx.x;  // 64 threads
    int b = bpool[c];
#pragma unroll
    for (int j = 0; j < 4; ++j)
        atomicAdd(&pb[b * 256 + t * 4 + j], z[(size_t)c * LD256 + t * 4 + j]);
}

__global__ void cntB_accum(const int* __restrict__ bpool, int* __restrict__ cntB, int n) {
    int c = blockIdx.x * blockDim.x + threadIdx.x;
    if (c < n) atomicAdd(&cntB[bpool[c]], 1);
}

// ---------------- heads ----------------

// logits0 + softmax + write x0 to d_out + build xb = [x0 | x_pool1]
__global__ void head0(const float* __restrict__ xp, const float* __restrict__ linW,
                      const float* __restrict__ linb, const float* __restrict__ xpool1,
                      float* __restrict__ outp, float* __restrict__ xb) {
    int r = blockIdx.x, t = threadIdx.x;  // 64 threads
    __shared__ float xr[256];
    __shared__ float lg[16];
    __shared__ float ex[16];
#pragma unroll
    for (int j = 0; j < 4; ++j) xr[t + 64 * j] = xp[(size_t)r * LD256 + t + 64 * j];
    __syncthreads();
    if (t < 16) {
        float acc = linb[t];
        for (int k = 0; k < 256; ++k) acc += xr[k] * linW[k * 16 + t];
        lg[t] = acc;
    }
    __syncthreads();
    if (t < 16) {
        float mx = lg[0];
#pragma unroll
        for (int c = 1; c < 16; ++c) mx = fmaxf(mx, lg[c]);
        ex[t] = expf(lg[t] - mx);
    }
    __syncthreads();
    if (t < 16) {
        float sum = 0.f;
#pragma unroll
        for (int c = 0; c < 16; ++c) sum += ex[c];
        float pv = ex[t] / sum;
        outp[(size_t)r * 16 + t] = pv;
        xb[(size_t)r * 17 + t] = pv;
    }
    if (t == 16) xb[(size_t)r * 17 + 16] = xpool1[r];
}

// final: mean(pb) -> layer2 GEMM+BN -> logits -> softmax -> d_out tail
__global__ void head1(const float* __restrict__ pb, const int* __restrict__ cntB,
                      const float* __restrict__ W, const float* __restrict__ bias,
                      const float* __restrict__ gam, const float* __restrict__ bet,
                      const float* __restrict__ mu, const float* __restrict__ var,
                      const float* __restrict__ linW, const float* __restrict__ linb,
                      float* __restrict__ outp) {
    int b = blockIdx.x, t = threadIdx.x;  // 256 threads
    __shared__ float pr[256];
    __shared__ float yr[256];
    __shared__ float lg[16];
    __shared__ float ex[16];
    int c = cntB[b];
    float inv = 1.0f / (float)max(c, 1);
    pr[t] = pb[b * 256 + t] * inv;
    __syncthreads();
    float acc = bias[t];
    for (int k = 0; k < 256; ++k) acc += pr[k] * W[k * 256 + t];
    float s = gam[t] * rsqrtf(var[t] + EPSc);
    acc = (acc - mu[t]) * s + bet[t];
    if (c == 0) acc = 0.f;
    yr[t] = acc;
    __syncthreads();
    if (t < 16) {
        float l = linb[t];
        for (int k = 0; k < 256; ++k) l += yr[k] * linW[k * 16 + t];
        lg[t] = l;
    }
    __syncthreads();
    if (t < 16) {
        float mx = lg[0];
#pragma unroll
        for (int cc = 1; cc < 16; ++cc) mx = fmaxf(mx, lg[cc]);
        ex[t] = expf(lg[t] - mx);
    }
    __syncthreads();
    if (t < 16) {
        float sum = 0.f;
#pragma unroll
        for (int cc = 0; cc < 16; ++cc) sum += ex[cc];
        outp[48000 + b * 16 + t] = ex[t] / sum;
    }
}

// ---------------- launch ----------------

extern "C" void kernel_launch(void* const* d_in, const int* in_sizes, int n_in,
                              void* d_out, int out_size, void* d_ws, size_t ws_size,
                              hipStream_t stream) {
    const float* x       = (const float*)d_in[0];
    const float* x_pool1 = (const float*)d_in[1];
    const float* W_in0   = (const float*)d_in[2];
    const float* W_h0    = (const float*)d_in[3];
    const float* b0      = (const float*)d_in[4];
    const float* g0      = (const float*)d_in[5];
    const float* be0     = (const float*)d_in[6];
    const float* m0      = (const float*)d_in[7];
    const float* v0      = (const float*)d_in[8];
    const float* W_in1   = (const float*)d_in[9];
    const float* W_h1    = (const float*)d_in[10];
    const float* b1      = (const float*)d_in[11];
    const float* g1      = (const float*)d_in[12];
    const float* be1     = (const float*)d_in[13];
    const float* m1      = (const float*)d_in[14];
    const float* v1      = (const float*)d_in[15];
    const float* linW0   = (const float*)d_in[16];
    const float* linb0   = (const float*)d_in[17];
    const float* linW1   = (const float*)d_in[18];
    const float* linb1   = (const float*)d_in[19];
    const int*   ei      = (const int*)d_in[20];
    const int*   batch   = (const int*)d_in[21];
    const int*   pool1   = (const int*)d_in[22];
    const int*   eip     = (const int*)d_in[23];
    float* outp = (float*)d_out;

    // carve workspace (256B-aligned)
    char* p = (char*)d_ws;
    auto carve = [&](size_t bytes) -> void* {
        void* r = (void*)p;
        p += (bytes + 255) & ~(size_t)255;
        return r;
    };
    int*   deg0   = (int*)  carve((size_t)N0c * 4);
    int*   tmp0   = (int*)  carve((size_t)N0c * 4);
    int*   rp0    = (int*)  carve((size_t)(N0c + 1) * 4);
    float* dinv0  = (float*)carve((size_t)N0c * 4);
    int*   blkSum = (int*)  carve(256 * 4);
    int*   blkOff = (int*)  carve(256 * 4);
    int2*  csw0   = (int2*) carve((size_t)E0c * 8);
    float* xpad   = (float*)carve((size_t)N0c * LD128 * 4);
    float* bufA   = (float*)carve((size_t)N0c * LD256 * 4);
    float* bufB   = (float*)carve((size_t)N0c * LD256 * 4);
    int*   start0 = (int*)  carve((size_t)(N1c + 1) * 4);
    int*   cnt0   = (int*)  carve((size_t)N1c * 4);
    float* pmean  = (float*)carve((size_t)N1c * LD256 * 4);
    float* xp     = (float*)carve((size_t)N1c * LD256 * 4);
    float* xb     = (float*)carve((size_t)N1c * 17 * 4);
    float* zb17   = (float*)carve((size_t)N1c * 17 * 4);
    int*   bpool  = (int*)  carve((size_t)N1c * 4);
    int*   deg1   = (int*)  carve((size_t)N1c * 4);
    int*   tmp1   = (int*)  carve((size_t)N1c * 4);
    int*   rp1    = (int*)  carve((size_t)(N1c + 1) * 4);
    float* dinv1  = (float*)carve((size_t)N1c * 4);
    int2*  csw1   = (int2*) carve((size_t)E1c * 8);
    float* zbb    = (float*)carve((size_t)N1c * LD256 * 4);
    float* hbb    = (float*)carve((size_t)N1c * LD256 * 4);
    float* pb     = (float*)carve((size_t)Bc * Hc * 4);
    int*   cntB   = (int*)  carve((size_t)Bc * 4);

    // zero-init accumulators (ws is poisoned every call)
    hipMemsetAsync(deg0, 0, (size_t)N0c * 4, stream);
    hipMemsetAsync(tmp0, 0, (size_t)N0c * 4, stream);
    hipMemsetAsync(deg1, 0, (size_t)N1c * 4, stream);
    hipMemsetAsync(tmp1, 0, (size_t)N1c * 4, stream);
    hipMemsetAsync(pb,   0, (size_t)Bc * Hc * 4, stream);
    hipMemsetAsync(cntB, 0, (size_t)Bc * 4, stream);

    const int* src0 = ei;
    const int* dst0 = ei + E0c;
    const int* src1 = eip;
    const int* dst1 = eip + E1c;

    // ---- graph 0 CSR ----
    count_deg<<<cdiv_i(E0c, 256), 256, 0, stream>>>(dst0, E0c, deg0);
    calc_dinv<<<cdiv_i(N0c, 256), 256, 0, stream>>>(deg0, dinv0, N0c);
    int nb0 = cdiv_i(N0c, 256);
    scan_block<<<nb0, 256, 0, stream>>>(deg0, N0c, rp0, blkSum);
    scan_sums<<<1, 256, 0, stream>>>(blkSum, nb0, blkOff, rp0, N0c);
    scan_add<<<nb0, 256, 0, stream>>>(rp0, N0c, blkOff);
    fill_csr<<<cdiv_i(E0c, 256), 256, 0, stream>>>(src0, dst0, E0c, rp0, tmp0, dinv0, csw0);
    pad_x128<<<cdiv_i(N0c * 32, 256), 256, 0, stream>>>(x, xpad);

    // ---- phase A: 3 GCN layers on N0, aggregate-first ----
    agg_wide<LD128v4, 4><<<4 * cdiv_i(N0c, 4), 256, 0, stream>>>(xpad, rp0, csw0, dinv0, bufA, N0c);
    gemm_bn<128, true, false><<<dim3(cdiv_i(N0c, 64), 4), 256, 0, stream>>>(
        bufA, W_in0, b0, g0, be0, m0, v0, nullptr, bufB, N0c, LD128, LD256);
    agg_wide<LD256v4, 8><<<8 * cdiv_i(N0c, 4), 256, 0, stream>>>(bufB, rp0, csw0, dinv0, bufA, N0c);
    gemm_bn<256, true, false><<<dim3(cdiv_i(N0c, 64), 4), 256, 0, stream>>>(
        bufA, W_h0, b0 + Hc, g0 + Hc, be0 + Hc, m0 + Hc, v0 + Hc, nullptr, bufB, N0c, LD256, LD256);
    agg_wide<LD256v4, 8><<<8 * cdiv_i(N0c, 4), 256, 0, stream>>>(bufB, rp0, csw0, dinv0, bufA, N0c);

    // layer 2: pool BEFORE GEMM (affine reorder); zero empty clusters in epilogue
    seg_starts<<<cdiv_i(N0c + 1, 256), 256, 0, stream>>>(pool1, N0c, N1c, start0);
    pool_mean<<<N1c, 64, 0, stream>>>(bufA, start0, batch, pmean, cnt0, bpool);
    gemm_bn<256, false, true><<<dim3(cdiv_i(N1c, 64), 4), 256, 0, stream>>>(
        pmean, W_h0 + Hc * Hc, b0 + 2 * Hc, g0 + 2 * Hc, be0 + 2 * Hc, m0 + 2 * Hc,
        v0 + 2 * Hc, cnt0, xp, N1c, LD256, LD256);

    // head0: logits + softmax -> d_out[0:48000], xb = [x0 | x_pool1]
    head0<<<N1c, 64, 0, stream>>>(xp, linW0, linb0, x_pool1, outp, xb);

    // ---- graph 1 CSR ----
    count_deg<<<cdiv_i(E1c, 256), 256, 0, stream>>>(dst1, E1c, deg1);
    calc_dinv<<<cdiv_i(N1c, 256), 256, 0, stream>>>(deg1, dinv1, N1c);
    int nb1 = cdiv_i(N1c, 256);
    scan_block<<<nb1, 256, 0, stream>>>(deg1, N1c, rp1, blkSum);
    scan_sums<<<1, 256, 0, stream>>>(blkSum, nb1, blkOff, rp1, N1c);
    scan_add<<<nb1, 256, 0, stream>>>(rp1, N1c, blkOff);
    fill_csr<<<cdiv_i(E1c, 256), 256, 0, stream>>>(src1, dst1, E1c, rp1, tmp1, dinv1, csw1);

    // ---- phase B: 3 GCN layers on N1 ----
    agg_small<<<N1c, 64, 0, stream>>>(xb, rp1, csw1, dinv1, zb17, 17);
    gemm17_bn_relu<<<N1c, 256, 0, stream>>>(zb17, W_in1, b1, g1, be1, m1, v1, hbb);
    agg_wide<LD256v4, 8><<<8 * cdiv_i(N1c, 4), 256, 0, stream>>>(hbb, rp1, csw1, dinv1, zbb, N1c);
    gemm_bn<256, true, false><<<dim3(cdiv_i(N1c, 64), 4), 256, 0, stream>>>(
        zbb, W_h1, b1 + Hc, g1 + Hc, be1 + Hc, m1 + Hc, v1 + Hc, nullptr, hbb, N1c, LD256, LD256);
    agg_wide<LD256v4, 8><<<8 * cdiv_i(N1c, 4), 256, 0, stream>>>(hbb, rp1, csw1, dinv1, zbb, N1c);

    // layer 2: pool to B graphs BEFORE GEMM (bpool is NOT sorted -> atomics)
    pool_b_accum<<<N1c, 64, 0, stream>>>(zbb, bpool, pb);
    cntB_accum<<<cdiv_i(N1c, 256), 256, 0, stream>>>(bpool, cntB, N1c);

    // head1: layer2 GEMM+BN + logits + softmax -> d_out[48000:48256]
    head1<<<Bc, 256, 0, stream>>>(pb, cntB, W_h1 + Hc * Hc, b1 + 2 * Hc, g1 + 2 * Hc,
                                  be1 + 2 * Hc, m1 + 2 * Hc, v1 + 2 * Hc, linW1, linb1,
                                  outp);
}

// Round 6
// 643.511 us; speedup vs baseline: 1.3201x; 1.3201x over previous
//
#include <hip/hip_runtime.h>
#include <cstdint>
#include <cstddef>

// Problem constants
#define N0c 30000
#define F0c 128
#define Hc  256
#define Cc  16
#define N1c 3000
#define Bc  16
#define E0c 960000
#define E1c 48000
#define NALL 33000            // N0 + N1 (concatenated graphs)
#define EALL 1008000          // E0 + E1
#define EPSc 1e-5f

static __host__ __device__ inline int cdiv_i(int a, int b) { return (a + b - 1) / b; }

// round-to-nearest-even fp32 -> bf16 (returns the 16 bf16 bits)
static __device__ inline unsigned short bfbits(float f) {
    unsigned u = __float_as_uint(f);
    return (unsigned short)((u + 0x7fffu + ((u >> 16) & 1u)) >> 16);
}

// ---------------- graph preprocessing (both graphs concatenated) ----------------

__global__ void count_deg_all(const int* __restrict__ dst0, const int* __restrict__ dst1,
                              int* __restrict__ deg) {
    int e = blockIdx.x * blockDim.x + threadIdx.x;
    if (e < E0c) atomicAdd(&deg[dst0[e]], 1);
    else if (e < EALL) atomicAdd(&deg[N0c + dst1[e - E0c]], 1);
}

__global__ void calc_dinv_all(const int* __restrict__ deg, float* __restrict__ dinv) {
    int i = blockIdx.x * blockDim.x + threadIdx.x;
    if (i < NALL) dinv[i] = rsqrtf((float)(deg[i] + 1));  // +1 self loop
}

// exclusive scan of deg[n] -> rp[n] (+ rp[n]=total), 3-kernel scan (nb<=256)
__global__ void scan_block(const int* __restrict__ cnt, int n, int* __restrict__ rp,
                           int* __restrict__ blkSum) {
    __shared__ int sh[256];
    int t = threadIdx.x;
    int i = blockIdx.x * 256 + t;
    int v = (i < n) ? cnt[i] : 0;
    sh[t] = v; __syncthreads();
    for (int off = 1; off < 256; off <<= 1) {
        int add = (t >= off) ? sh[t - off] : 0;
        __syncthreads();
        sh[t] += add;
        __syncthreads();
    }
    if (i < n) rp[i] = sh[t] - v;
    if (t == 255) blkSum[blockIdx.x] = sh[255];
}

__global__ void scan_sums(const int* __restrict__ blkSum, int nb, int* __restrict__ blkOff,
                          int* __restrict__ rp, int n) {
    __shared__ int sh[256];
    int t = threadIdx.x;
    int v = (t < nb) ? blkSum[t] : 0;
    sh[t] = v; __syncthreads();
    for (int off = 1; off < 256; off <<= 1) {
        int add = (t >= off) ? sh[t - off] : 0;
        __syncthreads();
        sh[t] += add;
        __syncthreads();
    }
    blkOff[t] = sh[t] - v;
    if (t == 255) rp[n] = sh[255];
}

__global__ void scan_add(int* __restrict__ rp, int n, const int* __restrict__ blkOff) {
    int i = blockIdx.x * 256 + threadIdx.x;
    if (i < n) rp[i] += blkOff[blockIdx.x];
}

// packed CSR entry: {w_bf16 : high16, src_u16 : low16} -> one 4B load per edge
__global__ void fill_csr_all(const int* __restrict__ src0, const int* __restrict__ dst0,
                             const int* __restrict__ src1, const int* __restrict__ dst1,
                             const int* __restrict__ rp, int* __restrict__ tmp,
                             const float* __restrict__ dinv, unsigned* __restrict__ csw) {
    int e = blockIdx.x * blockDim.x + threadIdx.x;
    if (e >= EALL) return;
    int s, d;
    if (e < E0c) { s = src0[e]; d = dst0[e]; }
    else         { s = N0c + src1[e - E0c]; d = N0c + dst1[e - E0c]; }
    int pos = rp[d] + atomicAdd(&tmp[d], 1);
    float w = dinv[s] * dinv[d];
    int sloc = (e < E0c) ? s : (s - N0c);   // local node id (fits u16)
    csw[pos] = ((unsigned)bfbits(w) << 16) | (unsigned)sloc;
}

// convert x (30000 x 128 fp32) -> bf16, compact stride 128
__global__ void cvt_x_bf16(const float* __restrict__ x, unsigned short* __restrict__ xb) {
    int i = blockIdx.x * 256 + threadIdx.x;  // float4 index
    if (i >= N0c * 32) return;
    float4 v = ((const float4*)x)[i];
    ushort4 o;
    o.x = bfbits(v.x); o.y = bfbits(v.y); o.z = bfbits(v.z); o.w = bfbits(v.w);
    ((ushort4*)xb)[i] = o;
}

// ---------------- aggregation (bf16 gather, fp32 accumulate/output) ----------------

static __device__ inline void acc8(float a[8], float w, uint4 v) {
    a[0] += w * __uint_as_float(v.x << 16);
    a[1] += w * __uint_as_float(v.x & 0xffff0000u);
    a[2] += w * __uint_as_float(v.y << 16);
    a[3] += w * __uint_as_float(v.y & 0xffff0000u);
    a[4] += w * __uint_as_float(v.z << 16);
    a[5] += w * __uint_as_float(v.z & 0xffff0000u);
    a[6] += w * __uint_as_float(v.w << 16);
    a[7] += w * __uint_as_float(v.w & 0xffff0000u);
}

// RSU: bf16 row stride in 16B units (16 for 128-wide, 32 for 256-wide).
// NCHUNK chunks of 64 cols; chunk = blockIdx&(NCHUNK-1) pins chunks to XCD sets
// (per-XCD gather slice ~3.8MB < 4MB L2). ORS4: fp32 out row stride in float4s.
// Block = 256 threads = 4 waves, one node per wave. lane = par*8+cl: par picks
// one of 8 edge slots, cl picks 16B (8 bf16 cols) within the 64-col chunk.
// Edge metadata batch-loaded 64-per-instruction (4B each), spread via __shfl.
template <int RSU, int NCHUNK, int ORS4>
__global__ __launch_bounds__(256) void agg_bf16(
    const unsigned short* __restrict__ x, const int* __restrict__ rp,
    const unsigned* __restrict__ csw, const float* __restrict__ dinv,
    float* __restrict__ z, int N) {
    int b = blockIdx.x;
    int chunk = b & (NCHUNK - 1);
    int node = (b / NCHUNK) * 4 + (threadIdx.x >> 6);
    if (node >= N) return;
    int lane = threadIdx.x & 63;
    int par = lane >> 3;
    int cl = lane & 7;
    int c4 = chunk * 8 + cl;             // uint4 index within bf16 row
    const uint4* x4 = (const uint4*)x;
    float a[8] = {0.f, 0.f, 0.f, 0.f, 0.f, 0.f, 0.f, 0.f};
    if (par == 0) {                      // self-loop term exactly once
        float di = dinv[node];
        uint4 v = x4[(size_t)node * RSU + c4];
        acc8(a, di * di, v);
    }
    int e0 = rp[node], e1 = rp[node + 1];
    for (int base = e0; base < e1; base += 64) {
        int avail = e1 - base;
        unsigned my = 0;
        if (lane < avail) my = csw[base + lane];   // 64 edges in ONE load
        int cnt = avail < 64 ? avail : 64;
#pragma unroll
        for (int i = 0; i < 8; ++i) {
            int idx = i * 8 + par;
            unsigned ew = (unsigned)__shfl((int)my, idx, 64);
            if (idx < cnt) {
                int sx = (int)(ew & 0xffffu);
                float w = __uint_as_float(ew & 0xffff0000u);
                uint4 v = x4[(size_t)sx * RSU + c4];
                acc8(a, w, v);
            }
        }
    }
#pragma unroll
    for (int m = 8; m < 64; m <<= 1) {
#pragma unroll
        for (int k = 0; k < 8; ++k) a[k] += __shfl_xor(a[k], m, 64);
    }
    if (par == 0) {
        float4* zp = (float4*)z + (size_t)node * ORS4 + chunk * 16 + cl * 2;
        zp[0] = make_float4(a[0], a[1], a[2], a[3]);
        zp[1] = make_float4(a[4], a[5], a[6], a[7]);
    }
}

// small F (17), scalar, fp32 x, packed csw
__global__ void agg_small(const float* __restrict__ x, const int* __restrict__ rp,
                          const unsigned* __restrict__ csw, const float* __restrict__ dinv,
                          float* __restrict__ z, int F) {
    int node = blockIdx.x;
    int t = threadIdx.x;
    if (t >= F) return;
    float di = dinv[node];
    float acc = di * di * x[(size_t)node * F + t];
    int e0 = rp[node], e1 = rp[node + 1];
    for (int e = e0; e < e1; ++e) {
        unsigned ew = csw[e];
        acc += __uint_as_float(ew & 0xffff0000u) * x[(size_t)(ew & 0xffffu) * F + t];
    }
    z[(size_t)node * F + t] = acc;
}

// ---------------- GEMM (M x K) @ (K x 256) + bias + BN (+ReLU) ----------------
// 64x64 tile, 256 threads, 4x4 microtile, BK=16. OBF16: write bf16 output.

template <int K, bool RELU, bool ZEROEMPTY, bool OBF16>
__global__ __launch_bounds__(256) void gemm_bn(
    const float* __restrict__ A, const float* __restrict__ W,
    const float* __restrict__ bias, const float* __restrict__ gam,
    const float* __restrict__ bet, const float* __restrict__ mu,
    const float* __restrict__ var, const int* __restrict__ cnt,
    void* __restrict__ outv, int M) {
    __shared__ __align__(16) float As[16][64];
    __shared__ __align__(16) float Bs[16][64];
    int tid = threadIdx.x;
    int tm = tid >> 4, tn = tid & 15;
    int row0 = blockIdx.x * 64, col0 = blockIdx.y * 64;
    float acc[4][4] = {};
    int ar = tid >> 2;
    int ak = (tid & 3) * 4;
    int bk = tid >> 4;
    int bn = (tid & 15) * 4;

    for (int kk = 0; kk < K; kk += 16) {
        float4 av = make_float4(0.f, 0.f, 0.f, 0.f);
        int grow = row0 + ar;
        if (grow < M) av = *(const float4*)(A + (size_t)grow * K + kk + ak);
        As[ak + 0][ar] = av.x;
        As[ak + 1][ar] = av.y;
        As[ak + 2][ar] = av.z;
        As[ak + 3][ar] = av.w;
        float4 bv = *(const float4*)(W + (size_t)(kk + bk) * 256 + col0 + bn);
        *(float4*)&Bs[bk][bn] = bv;
        __syncthreads();
#pragma unroll
        for (int k = 0; k < 16; ++k) {
            float4 a = *(const float4*)&As[k][tm * 4];
            float4 b = *(const float4*)&Bs[k][tn * 4];
            acc[0][0] += a.x * b.x; acc[0][1] += a.x * b.y; acc[0][2] += a.x * b.z; acc[0][3] += a.x * b.w;
            acc[1][0] += a.y * b.x; acc[1][1] += a.y * b.y; acc[1][2] += a.y * b.z; acc[1][3] += a.y * b.w;
            acc[2][0] += a.z * b.x; acc[2][1] += a.z * b.y; acc[2][2] += a.z * b.z; acc[2][3] += a.z * b.w;
            acc[3][0] += a.w * b.x; acc[3][1] += a.w * b.y; acc[3][2] += a.w * b.z; acc[3][3] += a.w * b.w;
        }
        __syncthreads();
    }
    float bcol[4], scol[4], mcol[4], ecol[4];
#pragma unroll
    for (int j = 0; j < 4; ++j) {
        int col = col0 + tn * 4 + j;
        bcol[j] = bias[col];
        scol[j] = gam[col] * rsqrtf(var[col] + EPSc);
        mcol[j] = mu[col];
        ecol[j] = bet[col];
    }
#pragma unroll
    for (int i = 0; i < 4; ++i) {
        int row = row0 + tm * 4 + i;
        if (row >= M) continue;
        bool zero = false;
        if (ZEROEMPTY) zero = (cnt[row] == 0);
        float r[4];
#pragma unroll
        for (int j = 0; j < 4; ++j) {
            float v = acc[i][j] + bcol[j];
            v = (v - mcol[j]) * scol[j] + ecol[j];
            if (RELU) v = fmaxf(v, 0.f);
            if (zero) v = 0.f;
            r[j] = v;
        }
        if (OBF16) {
            ushort4 o;
            o.x = bfbits(r[0]); o.y = bfbits(r[1]); o.z = bfbits(r[2]); o.w = bfbits(r[3]);
            *(ushort4*)((unsigned short*)outv + (size_t)row * 256 + col0 + tn * 4) = o;
        } else {
            float4 o = make_float4(r[0], r[1], r[2], r[3]);
            *(float4*)((float*)outv + (size_t)row * 256 + col0 + tn * 4) = o;
        }
    }
}

// K=17 GEMM: block per row, 256 threads, bf16 output (feeds agg)
__global__ void gemm17_bn_relu(const float* __restrict__ A, const float* __restrict__ W,
                               const float* __restrict__ bias, const float* __restrict__ gam,
                               const float* __restrict__ bet, const float* __restrict__ mu,
                               const float* __restrict__ var, unsigned short* __restrict__ out) {
    int r = blockIdx.x, t = threadIdx.x;
    __shared__ float zr[17];
    if (t < 17) zr[t] = A[(size_t)r * 17 + t];
    __syncthreads();
    float acc = bias[t];
#pragma unroll
    for (int k = 0; k < 17; ++k) acc += zr[k] * W[k * 256 + t];
    float s = gam[t] * rsqrtf(var[t] + EPSc);
    acc = (acc - mu[t]) * s + bet[t];
    acc = fmaxf(acc, 0.f);
    out[(size_t)r * 256 + t] = bfbits(acc);
}

// ---------------- pooling ----------------

__global__ void seg_starts(const int* __restrict__ pool, int n, int nseg,
                           int* __restrict__ start) {
    int i = blockIdx.x * blockDim.x + threadIdx.x;
    if (i > n) return;
    if (i == 0) {
        for (int c = 0; c <= pool[0]; ++c) start[c] = 0;
    } else if (i == n) {
        for (int c = pool[n - 1] + 1; c <= nseg; ++c) start[c] = n;
    } else {
        int a = pool[i - 1], b = pool[i];
        for (int c = a + 1; c <= b; ++c) start[c] = i;
    }
}

__global__ void pool_mean(const float* __restrict__ z, const int* __restrict__ start,
                          const int* __restrict__ batch, float* __restrict__ p,
                          int* __restrict__ cnt_out, int* __restrict__ bpool) {
    int c = blockIdx.x, t = threadIdx.x;  // 64 threads
    int s = start[c], e = start[c + 1];
    int cnt = e - s;
    const float4* z4 = (const float4*)z;
    float ax = 0.f, ay = 0.f, az = 0.f, aw = 0.f;
    for (int i = s; i < e; ++i) {
        float4 v = z4[(size_t)i * 64 + t];
        ax += v.x; ay += v.y; az += v.z; aw += v.w;
    }
    float inv = 1.0f / (float)max(cnt, 1);
    ((float4*)p)[(size_t)c * 64 + t] = make_float4(ax * inv, ay * inv, az * inv, aw * inv);
    if (t == 0) {
        cnt_out[c] = cnt;
        int sb = 0;
        for (int i = s; i < e; ++i) sb += batch[i];
        bpool[c] = (int)rintf((float)sb * inv);
    }
}

__global__ void pool_b_accum(const float* __restrict__ z, const int* __restrict__ bpool,
                             float* __restrict__ pb) {
    int c = blockIdx.x, t = threadIdx.x;  // 64 threads
    int b = bpool[c];
#pragma unroll
    for (int j = 0; j < 4; ++j)
        atomicAdd(&pb[b * 256 + t * 4 + j], z[(size_t)c * 256 + t * 4 + j]);
}

__global__ void cntB_accum(const int* __restrict__ bpool, int* __restrict__ cntB, int n) {
    int c = blockIdx.x * blockDim.x + threadIdx.x;
    if (c < n) atomicAdd(&cntB[bpool[c]], 1);
}

// ---------------- heads ----------------

__global__ void head0(const float* __restrict__ xp, const float* __restrict__ linW,
                      const float* __restrict__ linb, const float* __restrict__ xpool1,
                      float* __restrict__ outp, float* __restrict__ xb) {
    int r = blockIdx.x, t = threadIdx.x;  // 64 threads
    __shared__ float xr[256];
    __shared__ float lg[16];
    __shared__ float ex[16];
#pragma unroll
    for (int j = 0; j < 4; ++j) xr[t + 64 * j] = xp[(size_t)r * 256 + t + 64 * j];
    __syncthreads();
    if (t < 16) {
        float acc = linb[t];
        for (int k = 0; k < 256; ++k) acc += xr[k] * linW[k * 16 + t];
        lg[t] = acc;
    }
    __syncthreads();
    if (t < 16) {
        float mx = lg[0];
#pragma unroll
        for (int c = 1; c < 16; ++c) mx = fmaxf(mx, lg[c]);
        ex[t] = expf(lg[t] - mx);
    }
    __syncthreads();
    if (t < 16) {
        float sum = 0.f;
#pragma unroll
        for (int c = 0; c < 16; ++c) sum += ex[c];
        float pv = ex[t] / sum;
        outp[(size_t)r * 16 + t] = pv;
        xb[(size_t)r * 17 + t] = pv;
    }
    if (t == 16) xb[(size_t)r * 17 + 16] = xpool1[r];
}

__global__ void head1(const float* __restrict__ pb, const int* __restrict__ cntB,
                      const float* __restrict__ W, const float* __restrict__ bias,
                      const float* __restrict__ gam, const float* __restrict__ bet,
                      const float* __restrict__ mu, const float* __restrict__ var,
                      const float* __restrict__ linW, const float* __restrict__ linb,
                      float* __restrict__ outp) {
    int b = blockIdx.x, t = threadIdx.x;  // 256 threads
    __shared__ float pr[256];
    __shared__ float yr[256];
    __shared__ float lg[16];
    __shared__ float ex[16];
    int c = cntB[b];
    float inv = 1.0f / (float)max(c, 1);
    pr[t] = pb[b * 256 + t] * inv;
    __syncthreads();
    float acc = bias[t];
    for (int k = 0; k < 256; ++k) acc += pr[k] * W[k * 256 + t];
    float s = gam[t] * rsqrtf(var[t] + EPSc);
    acc = (acc - mu[t]) * s + bet[t];
    if (c == 0) acc = 0.f;
    yr[t] = acc;
    __syncthreads();
    if (t < 16) {
        float l = linb[t];
        for (int k = 0; k < 256; ++k) l += yr[k] * linW[k * 16 + t];
        lg[t] = l;
    }
    __syncthreads();
    if (t < 16) {
        float mx = lg[0];
#pragma unroll
        for (int cc = 1; cc < 16; ++cc) mx = fmaxf(mx, lg[cc]);
        ex[t] = expf(lg[t] - mx);
    }
    __syncthreads();
    if (t < 16) {
        float sum = 0.f;
#pragma unroll
        for (int cc = 0; cc < 16; ++cc) sum += ex[cc];
        outp[48000 + b * 16 + t] = ex[t] / sum;
    }
}

// ---------------- launch ----------------

extern "C" void kernel_launch(void* const* d_in, const int* in_sizes, int n_in,
                              void* d_out, int out_size, void* d_ws, size_t ws_size,
                              hipStream_t stream) {
    const float* x       = (const float*)d_in[0];
    const float* x_pool1 = (const float*)d_in[1];
    const float* W_in0   = (const float*)d_in[2];
    const float* W_h0    = (const float*)d_in[3];
    const float* b0      = (const float*)d_in[4];
    const float* g0      = (const float*)d_in[5];
    const float* be0     = (const float*)d_in[6];
    const float* m0      = (const float*)d_in[7];
    const float* v0      = (const float*)d_in[8];
    const float* W_in1   = (const float*)d_in[9];
    const float* W_h1    = (const float*)d_in[10];
    const float* b1      = (const float*)d_in[11];
    const float* g1      = (const float*)d_in[12];
    const float* be1     = (const float*)d_in[13];
    const float* m1      = (const float*)d_in[14];
    const float* v1      = (const float*)d_in[15];
    const float* linW0   = (const float*)d_in[16];
    const float* linb0   = (const float*)d_in[17];
    const float* linW1   = (const float*)d_in[18];
    const float* linb1   = (const float*)d_in[19];
    const int*   ei      = (const int*)d_in[20];
    const int*   batch   = (const int*)d_in[21];
    const int*   pool1   = (const int*)d_in[22];
    const int*   eip     = (const int*)d_in[23];
    float* outp = (float*)d_out;

    // carve workspace (256B-aligned); zero-init block FIRST (single memset)
    char* p = (char*)d_ws;
    auto carve = [&](size_t bytes) -> void* {
        void* r = (void*)p;
        p += (bytes + 255) & ~(size_t)255;
        return r;
    };
    int*   deg    = (int*)  carve((size_t)NALL * 4);   // zeroed
    int*   tmp    = (int*)  carve((size_t)NALL * 4);   // zeroed
    float* pb     = (float*)carve((size_t)Bc * Hc * 4);// zeroed
    int*   cntB   = (int*)  carve((size_t)Bc * 4);     // zeroed
    size_t zeroBytes = (size_t)((char*)p - (char*)deg);

    int*   rp     = (int*)  carve((size_t)(NALL + 1) * 4);
    float* dinv   = (float*)carve((size_t)NALL * 4);
    int*   blkSum = (int*)  carve(256 * 4);
    int*   blkOff = (int*)  carve(256 * 4);
    unsigned* csw = (unsigned*)carve((size_t)EALL * 4);
    unsigned short* xbf   = (unsigned short*)carve((size_t)N0c * 128 * 2);
    unsigned short* bufbf = (unsigned short*)carve((size_t)N0c * 256 * 2);
    float* bufA   = (float*)carve((size_t)N0c * 256 * 4);
    int*   start0 = (int*)  carve((size_t)(N1c + 1) * 4);
    int*   cnt0   = (int*)  carve((size_t)N1c * 4);
    float* pmean  = (float*)carve((size_t)N1c * 256 * 4);
    float* xp     = (float*)carve((size_t)N1c * 256 * 4);
    float* xb     = (float*)carve((size_t)N1c * 17 * 4);
    float* zb17   = (float*)carve((size_t)N1c * 17 * 4);
    int*   bpool  = (int*)  carve((size_t)N1c * 4);
    unsigned short* hbbbf = (unsigned short*)carve((size_t)N1c * 256 * 2);
    float* zbb    = (float*)carve((size_t)N1c * 256 * 4);

    hipMemsetAsync(deg, 0, zeroBytes, stream);

    const int* src0 = ei;
    const int* dst0 = ei + E0c;
    const int* src1 = eip;
    const int* dst1 = eip + E1c;

    // ---- unified CSR build (both graphs concatenated: nodes [0,33000)) ----
    count_deg_all<<<cdiv_i(EALL, 256), 256, 0, stream>>>(dst0, dst1, deg);
    calc_dinv_all<<<cdiv_i(NALL, 256), 256, 0, stream>>>(deg, dinv);
    int nb = cdiv_i(NALL, 256);
    scan_block<<<nb, 256, 0, stream>>>(deg, NALL, rp, blkSum);
    scan_sums<<<1, 256, 0, stream>>>(blkSum, nb, blkOff, rp, NALL);
    scan_add<<<nb, 256, 0, stream>>>(rp, NALL, blkOff);
    fill_csr_all<<<cdiv_i(EALL, 256), 256, 0, stream>>>(src0, dst0, src1, dst1, rp, tmp, dinv, csw);
    cvt_x_bf16<<<cdiv_i(N0c * 32, 256), 256, 0, stream>>>(x, xbf);

    // graph-1 views into the concatenated CSR
    const int*   rp1   = rp + N0c;
    const float* dinv1 = dinv + N0c;

    // ---- phase A: 3 GCN layers on N0, aggregate-first ----
    agg_bf16<16, 2, 32><<<2 * cdiv_i(N0c, 4), 256, 0, stream>>>(xbf, rp, csw, dinv, bufA, N0c);
    gemm_bn<128, true, false, true><<<dim3(cdiv_i(N0c, 64), 4), 256, 0, stream>>>(
        bufA, W_in0, b0, g0, be0, m0, v0, nullptr, bufbf, N0c);
    agg_bf16<32, 4, 64><<<4 * cdiv_i(N0c, 4), 256, 0, stream>>>(bufbf, rp, csw, dinv, bufA, N0c);
    gemm_bn<256, true, false, true><<<dim3(cdiv_i(N0c, 64), 4), 256, 0, stream>>>(
        bufA, W_h0, b0 + Hc, g0 + Hc, be0 + Hc, m0 + Hc, v0 + Hc, nullptr, bufbf, N0c);
    agg_bf16<32, 4, 64><<<4 * cdiv_i(N0c, 4), 256, 0, stream>>>(bufbf, rp, csw, dinv, bufA, N0c);

    // layer 2: pool BEFORE GEMM (affine reorder); zero empty clusters in epilogue
    seg_starts<<<cdiv_i(N0c + 1, 256), 256, 0, stream>>>(pool1, N0c, N1c, start0);
    pool_mean<<<N1c, 64, 0, stream>>>(bufA, start0, batch, pmean, cnt0, bpool);
    gemm_bn<256, false, true, false><<<dim3(cdiv_i(N1c, 64), 4), 256, 0, stream>>>(
        pmean, W_h0 + Hc * Hc, b0 + 2 * Hc, g0 + 2 * Hc, be0 + 2 * Hc, m0 + 2 * Hc,
        v0 + 2 * Hc, cnt0, xp, N1c);

    // head0: logits + softmax -> d_out[0:48000], xb = [x0 | x_pool1]
    head0<<<N1c, 64, 0, stream>>>(xp, linW0, linb0, x_pool1, outp, xb);

    // ---- phase B: 3 GCN layers on N1 ----
    agg_small<<<N1c, 64, 0, stream>>>(xb, rp1, csw, dinv1, zb17, 17);
    gemm17_bn_relu<<<N1c, 256, 0, stream>>>(zb17, W_in1, b1, g1, be1, m1, v1, hbbbf);
    agg_bf16<32, 4, 64><<<4 * cdiv_i(N1c, 4), 256, 0, stream>>>(hbbbf, rp1, csw, dinv1, zbb, N1c);
    gemm_bn<256, true, false, true><<<dim3(cdiv_i(N1c, 64), 4), 256, 0, stream>>>(
        zbb, W_h1, b1 + Hc, g1 + Hc, be1 + Hc, m1 + Hc, v1 + Hc, nullptr, hbbbf, N1c);
    agg_bf16<32, 4, 64><<<4 * cdiv_i(N1c, 4), 256, 0, stream>>>(hbbbf, rp1, csw, dinv1, zbb, N1c);

    // layer 2: pool to B graphs BEFORE GEMM (bpool is NOT sorted -> atomics)
    pool_b_accum<<<N1c, 64, 0, stream>>>(zbb, bpool, pb);
    cntB_accum<<<cdiv_i(N1c, 256), 256, 0, stream>>>(bpool, cntB, N1c);

    // head1: layer2 GEMM+BN + logits + softmax -> d_out[48000:48256]
    head1<<<Bc, 256, 0, stream>>>(pb, cntB, W_h1 + Hc * Hc, b1 + 2 * Hc, g1 + 2 * Hc,
                                  be1 + 2 * Hc, m1 + 2 * Hc, v1 + 2 * Hc, linW1, linb1,
                                  outp);
}

// Round 7
// 581.762 us; speedup vs baseline: 1.4603x; 1.1061x over previous
//
#include <hip/hip_runtime.h>
#include <cstdint>
#include <cstddef>

// Problem constants
#define N0c 30000
#define F0c 128
#define Hc  256
#define Cc  16
#define N1c 3000
#define Bc  16
#define E0c 960000
#define E1c 48000
#define NALL 33000            // N0 + N1 (concatenated graphs)
#define EALL 1008000          // E0 + E1
#define EPSc 1e-5f

static __host__ __device__ inline int cdiv_i(int a, int b) { return (a + b - 1) / b; }

// round-to-nearest-even fp32 -> bf16 (returns the 16 bf16 bits)
static __device__ inline unsigned short bfbits(float f) {
    unsigned u = __float_as_uint(f);
    return (unsigned short)((u + 0x7fffu + ((u >> 16) & 1u)) >> 16);
}

typedef short short8 __attribute__((ext_vector_type(8)));   // 8 bf16 = 4 VGPRs
typedef float floatx4 __attribute__((ext_vector_type(4)));

// ---------------- graph preprocessing (both graphs concatenated) ----------------

__global__ void count_deg_all(const int* __restrict__ dst0, const int* __restrict__ dst1,
                              int* __restrict__ deg) {
    int e = blockIdx.x * blockDim.x + threadIdx.x;
    if (e < E0c) atomicAdd(&deg[dst0[e]], 1);
    else if (e < EALL) atomicAdd(&deg[N0c + dst1[e - E0c]], 1);
}

__global__ void calc_dinv_all(const int* __restrict__ deg, float* __restrict__ dinv) {
    int i = blockIdx.x * blockDim.x + threadIdx.x;
    if (i < NALL) dinv[i] = rsqrtf((float)(deg[i] + 1));  // +1 self loop
}

__global__ void scan_block(const int* __restrict__ cnt, int n, int* __restrict__ rp,
                           int* __restrict__ blkSum) {
    __shared__ int sh[256];
    int t = threadIdx.x;
    int i = blockIdx.x * 256 + t;
    int v = (i < n) ? cnt[i] : 0;
    sh[t] = v; __syncthreads();
    for (int off = 1; off < 256; off <<= 1) {
        int add = (t >= off) ? sh[t - off] : 0;
        __syncthreads();
        sh[t] += add;
        __syncthreads();
    }
    if (i < n) rp[i] = sh[t] - v;
    if (t == 255) blkSum[blockIdx.x] = sh[255];
}

__global__ void scan_sums(const int* __restrict__ blkSum, int nb, int* __restrict__ blkOff,
                          int* __restrict__ rp, int n) {
    __shared__ int sh[256];
    int t = threadIdx.x;
    int v = (t < nb) ? blkSum[t] : 0;
    sh[t] = v; __syncthreads();
    for (int off = 1; off < 256; off <<= 1) {
        int add = (t >= off) ? sh[t - off] : 0;
        __syncthreads();
        sh[t] += add;
        __syncthreads();
    }
    blkOff[t] = sh[t] - v;
    if (t == 255) rp[n] = sh[255];
}

__global__ void scan_add(int* __restrict__ rp, int n, const int* __restrict__ blkOff) {
    int i = blockIdx.x * 256 + threadIdx.x;
    if (i < n) rp[i] += blkOff[blockIdx.x];
}

// packed CSR entry: {w_bf16 : high16, src_u16 : low16} -> one 4B load per edge
__global__ void fill_csr_all(const int* __restrict__ src0, const int* __restrict__ dst0,
                             const int* __restrict__ src1, const int* __restrict__ dst1,
                             const int* __restrict__ rp, int* __restrict__ tmp,
                             const float* __restrict__ dinv, unsigned* __restrict__ csw) {
    int e = blockIdx.x * blockDim.x + threadIdx.x;
    if (e >= EALL) return;
    int s, d;
    if (e < E0c) { s = src0[e]; d = dst0[e]; }
    else         { s = N0c + src1[e - E0c]; d = N0c + dst1[e - E0c]; }
    int pos = rp[d] + atomicAdd(&tmp[d], 1);
    float w = dinv[s] * dinv[d];
    int sloc = (e < E0c) ? s : (s - N0c);   // local node id (fits u16)
    csw[pos] = ((unsigned)bfbits(w) << 16) | (unsigned)sloc;
}

// convert x (30000 x 128 fp32) -> bf16
__global__ void cvt_x_bf16(const float* __restrict__ x, unsigned short* __restrict__ xb) {
    int i = blockIdx.x * 256 + threadIdx.x;  // float4 index
    if (i >= N0c * 32) return;
    float4 v = ((const float4*)x)[i];
    ushort4 o;
    o.x = bfbits(v.x); o.y = bfbits(v.y); o.z = bfbits(v.z); o.w = bfbits(v.w);
    ((ushort4*)xb)[i] = o;
}

// transpose + convert W (K x 256 fp32) -> Wt (256 x K bf16)
__global__ void cvt_wt(const float* __restrict__ W, unsigned short* __restrict__ Wt, int K) {
    int i = blockIdx.x * 256 + threadIdx.x;
    if (i >= K * 256) return;
    int k = i >> 8, col = i & 255;
    Wt[col * K + k] = bfbits(W[i]);
}

// fold bias+BN into per-col scale/shift: out = v*sc + sh
__global__ void bn_coef(const float* __restrict__ bias, const float* __restrict__ gam,
                        const float* __restrict__ bet, const float* __restrict__ mu,
                        const float* __restrict__ var, float* __restrict__ sc,
                        float* __restrict__ sh) {
    int t = threadIdx.x;
    float s = gam[t] * rsqrtf(var[t] + EPSc);
    sc[t] = s;
    sh[t] = (bias[t] - mu[t]) * s + bet[t];
}

// ---------------- aggregation (bf16 gather, fp32 accumulate) ----------------

static __device__ inline void acc8(float a[8], float w, uint4 v) {
    a[0] += w * __uint_as_float(v.x << 16);
    a[1] += w * __uint_as_float(v.x & 0xffff0000u);
    a[2] += w * __uint_as_float(v.y << 16);
    a[3] += w * __uint_as_float(v.y & 0xffff0000u);
    a[4] += w * __uint_as_float(v.z << 16);
    a[5] += w * __uint_as_float(v.z & 0xffff0000u);
    a[6] += w * __uint_as_float(v.w << 16);
    a[7] += w * __uint_as_float(v.w & 0xffff0000u);
}

// RSU: bf16 row stride in 16B units (16 for 128-wide, 32 for 256-wide).
// NCHUNK chunks of 64 cols; chunk = blockIdx&(NCHUNK-1) pins chunks to XCD sets.
// OBF16: write output as packed bf16 (feeds MFMA GEMM); else fp32.
template <int RSU, int NCHUNK, bool OBF16>
__global__ __launch_bounds__(256) void agg_bf16(
    const unsigned short* __restrict__ x, const int* __restrict__ rp,
    const unsigned* __restrict__ csw, const float* __restrict__ dinv,
    void* __restrict__ zv, int N) {
    int b = blockIdx.x;
    int chunk = b & (NCHUNK - 1);
    int node = (b / NCHUNK) * 4 + (threadIdx.x >> 6);
    if (node >= N) return;
    int lane = threadIdx.x & 63;
    int par = lane >> 3;
    int cl = lane & 7;
    int c4 = chunk * 8 + cl;             // uint4 index within bf16 row
    const uint4* x4 = (const uint4*)x;
    float a[8] = {0.f, 0.f, 0.f, 0.f, 0.f, 0.f, 0.f, 0.f};
    if (par == 0) {                      // self-loop term exactly once
        float di = dinv[node];
        uint4 v = x4[(size_t)node * RSU + c4];
        acc8(a, di * di, v);
    }
    int e0 = rp[node], e1 = rp[node + 1];
    for (int base = e0; base < e1; base += 64) {
        int avail = e1 - base;
        unsigned my = 0;
        if (lane < avail) my = csw[base + lane];   // 64 edges in ONE load
        int cnt = avail < 64 ? avail : 64;
#pragma unroll
        for (int i = 0; i < 8; ++i) {
            int idx = i * 8 + par;
            unsigned ew = (unsigned)__shfl((int)my, idx, 64);
            if (idx < cnt) {
                int sx = (int)(ew & 0xffffu);
                float w = __uint_as_float(ew & 0xffff0000u);
                uint4 v = x4[(size_t)sx * RSU + c4];
                acc8(a, w, v);
            }
        }
    }
#pragma unroll
    for (int m = 8; m < 64; m <<= 1) {
#pragma unroll
        for (int k = 0; k < 8; ++k) a[k] += __shfl_xor(a[k], m, 64);
    }
    if (par == 0) {
        if (OBF16) {
            uint4 o;
            o.x = (unsigned)bfbits(a[0]) | ((unsigned)bfbits(a[1]) << 16);
            o.y = (unsigned)bfbits(a[2]) | ((unsigned)bfbits(a[3]) << 16);
            o.z = (unsigned)bfbits(a[4]) | ((unsigned)bfbits(a[5]) << 16);
            o.w = (unsigned)bfbits(a[6]) | ((unsigned)bfbits(a[7]) << 16);
            ((uint4*)zv)[(size_t)node * RSU + c4] = o;
        } else {
            float4* zp = (float4*)zv + (size_t)node * (RSU * 2) + c4 * 2;
            zp[0] = make_float4(a[0], a[1], a[2], a[3]);
            zp[1] = make_float4(a[4], a[5], a[6], a[7]);
        }
    }
}

// small F (17), scalar, fp32 x, packed csw
__global__ void agg_small(const float* __restrict__ x, const int* __restrict__ rp,
                          const unsigned* __restrict__ csw, const float* __restrict__ dinv,
                          float* __restrict__ z, int F) {
    int node = blockIdx.x;
    int t = threadIdx.x;
    if (t >= F) return;
    float di = dinv[node];
    float acc = di * di * x[(size_t)node * F + t];
    int e0 = rp[node], e1 = rp[node + 1];
    for (int e = e0; e < e1; ++e) {
        unsigned ew = csw[e];
        acc += __uint_as_float(ew & 0xffff0000u) * x[(size_t)(ew & 0xffffu) * F + t];
    }
    z[(size_t)node * F + t] = acc;
}

// ---------------- MFMA bf16 GEMM: (M x K)bf16 @ Wt(256 x K)bf16 -> bf16 out ----
// Block tile 64(M) x 256(N), 256 threads = 4 waves; wave w owns cols [w*64,w*64+64)
// over all 64 rows (4x4 MFMA 16x16x32 subtiles). Epilogue: v*sc+sh, ReLU, bf16.
// LDS stride 40 shorts: b128 accesses land 8 lanes/bank uniformly (= b128 floor).

template <int K>
__global__ __launch_bounds__(256) void gemm_mfma_bn(
    const unsigned short* __restrict__ A, const unsigned short* __restrict__ Wt,
    const float* __restrict__ sc, const float* __restrict__ sh,
    unsigned short* __restrict__ out, int M) {
    constexpr int LDS_S = 40;
    __shared__ unsigned short As[64 * LDS_S];
    __shared__ unsigned short Bs[256 * LDS_S];
    int tid = threadIdx.x;
    int w = tid >> 6, l = tid & 63;
    int quad = l >> 4, lm = l & 15;
    int row0 = blockIdx.x * 64;
    floatx4 acc[4][4];
#pragma unroll
    for (int i = 0; i < 4; ++i)
#pragma unroll
        for (int j = 0; j < 4; ++j) acc[i][j] = (floatx4){0.f, 0.f, 0.f, 0.f};

    int ar = tid >> 2;          // A staging: row 0..63
    int ac = (tid & 3) * 8;     // short offset 0,8,16,24

    for (int k0 = 0; k0 < K; k0 += 32) {
        uint4 av = make_uint4(0, 0, 0, 0);
        if (row0 + ar < M) av = *(const uint4*)(A + (size_t)(row0 + ar) * K + k0 + ac);
        *(uint4*)&As[ar * LDS_S + ac] = av;
#pragma unroll
        for (int c = 0; c < 4; ++c) {    // Bs: thread -> col tid, 4 k-chunks
            uint4 bv = *(const uint4*)(Wt + (size_t)tid * K + k0 + c * 8);
            *(uint4*)&Bs[tid * LDS_S + c * 8] = bv;
        }
        __syncthreads();
        short8 af[4], bf[4];
#pragma unroll
        for (int i = 0; i < 4; ++i)
            af[i] = *(const short8*)&As[(i * 16 + lm) * LDS_S + quad * 8];
#pragma unroll
        for (int j = 0; j < 4; ++j)
            bf[j] = *(const short8*)&Bs[(w * 64 + j * 16 + lm) * LDS_S + quad * 8];
#pragma unroll
        for (int i = 0; i < 4; ++i)
#pragma unroll
            for (int j = 0; j < 4; ++j)
                acc[i][j] = __builtin_amdgcn_mfma_f32_16x16x32_bf16(af[i], bf[j], acc[i][j], 0, 0, 0);
        __syncthreads();
    }
    // epilogue: C/D map col=lane&15, row=quad*4+reg [verified m89/m91]
#pragma unroll
    for (int j = 0; j < 4; ++j) {
        int col = w * 64 + j * 16 + lm;
        float s = sc[col], h = sh[col];
#pragma unroll
        for (int i = 0; i < 4; ++i) {
            int rb = row0 + i * 16 + quad * 4;
#pragma unroll
            for (int r = 0; r < 4; ++r) {
                int row = rb + r;
                if (row < M) {
                    float v = acc[i][j][r] * s + h;
                    v = fmaxf(v, 0.f);
                    out[(size_t)row * 256 + col] = bfbits(v);
                }
            }
        }
    }
}

// ---------------- fp32 vector GEMM (kept for small M=3000, precision-critical) --

template <int K, bool RELU, bool ZEROEMPTY, bool OBF16>
__global__ __launch_bounds__(256) void gemm_bn(
    const float* __restrict__ A, const float* __restrict__ W,
    const float* __restrict__ bias, const float* __restrict__ gam,
    const float* __restrict__ bet, const float* __restrict__ mu,
    const float* __restrict__ var, const int* __restrict__ cnt,
    void* __restrict__ outv, int M) {
    __shared__ __align__(16) float As[16][64];
    __shared__ __align__(16) float Bs[16][64];
    int tid = threadIdx.x;
    int tm = tid >> 4, tn = tid & 15;
    int row0 = blockIdx.x * 64, col0 = blockIdx.y * 64;
    float acc[4][4] = {};
    int ar = tid >> 2;
    int ak = (tid & 3) * 4;
    int bk = tid >> 4;
    int bn = (tid & 15) * 4;

    for (int kk = 0; kk < K; kk += 16) {
        float4 av = make_float4(0.f, 0.f, 0.f, 0.f);
        int grow = row0 + ar;
        if (grow < M) av = *(const float4*)(A + (size_t)grow * K + kk + ak);
        As[ak + 0][ar] = av.x;
        As[ak + 1][ar] = av.y;
        As[ak + 2][ar] = av.z;
        As[ak + 3][ar] = av.w;
        float4 bv = *(const float4*)(W + (size_t)(kk + bk) * 256 + col0 + bn);
        *(float4*)&Bs[bk][bn] = bv;
        __syncthreads();
#pragma unroll
        for (int k = 0; k < 16; ++k) {
            float4 a = *(const float4*)&As[k][tm * 4];
            float4 b = *(const float4*)&Bs[k][tn * 4];
            acc[0][0] += a.x * b.x; acc[0][1] += a.x * b.y; acc[0][2] += a.x * b.z; acc[0][3] += a.x * b.w;
            acc[1][0] += a.y * b.x; acc[1][1] += a.y * b.y; acc[1][2] += a.y * b.z; acc[1][3] += a.y * b.w;
            acc[2][0] += a.z * b.x; acc[2][1] += a.z * b.y; acc[2][2] += a.z * b.z; acc[2][3] += a.z * b.w;
            acc[3][0] += a.w * b.x; acc[3][1] += a.w * b.y; acc[3][2] += a.w * b.z; acc[3][3] += a.w * b.w;
        }
        __syncthreads();
    }
    float bcol[4], scol[4], mcol[4], ecol[4];
#pragma unroll
    for (int j = 0; j < 4; ++j) {
        int col = col0 + tn * 4 + j;
        bcol[j] = bias[col];
        scol[j] = gam[col] * rsqrtf(var[col] + EPSc);
        mcol[j] = mu[col];
        ecol[j] = bet[col];
    }
#pragma unroll
    for (int i = 0; i < 4; ++i) {
        int row = row0 + tm * 4 + i;
        if (row >= M) continue;
        bool zero = false;
        if (ZEROEMPTY) zero = (cnt[row] == 0);
        float r[4];
#pragma unroll
        for (int j = 0; j < 4; ++j) {
            float v = acc[i][j] + bcol[j];
            v = (v - mcol[j]) * scol[j] + ecol[j];
            if (RELU) v = fmaxf(v, 0.f);
            if (zero) v = 0.f;
            r[j] = v;
        }
        if (OBF16) {
            ushort4 o;
            o.x = bfbits(r[0]); o.y = bfbits(r[1]); o.z = bfbits(r[2]); o.w = bfbits(r[3]);
            *(ushort4*)((unsigned short*)outv + (size_t)row * 256 + col0 + tn * 4) = o;
        } else {
            float4 o = make_float4(r[0], r[1], r[2], r[3]);
            *(float4*)((float*)outv + (size_t)row * 256 + col0 + tn * 4) = o;
        }
    }
}

// K=17 GEMM: block per row, 256 threads, bf16 output (feeds agg)
__global__ void gemm17_bn_relu(const float* __restrict__ A, const float* __restrict__ W,
                               const float* __restrict__ bias, const float* __restrict__ gam,
                               const float* __restrict__ bet, const float* __restrict__ mu,
                               const float* __restrict__ var, unsigned short* __restrict__ out) {
    int r = blockIdx.x, t = threadIdx.x;
    __shared__ float zr[17];
    if (t < 17) zr[t] = A[(size_t)r * 17 + t];
    __syncthreads();
    float acc = bias[t];
#pragma unroll
    for (int k = 0; k < 17; ++k) acc += zr[k] * W[k * 256 + t];
    float s = gam[t] * rsqrtf(var[t] + EPSc);
    acc = (acc - mu[t]) * s + bet[t];
    acc = fmaxf(acc, 0.f);
    out[(size_t)r * 256 + t] = bfbits(acc);
}

// ---------------- pooling ----------------

__global__ void seg_starts(const int* __restrict__ pool, int n, int nseg,
                           int* __restrict__ start) {
    int i = blockIdx.x * blockDim.x + threadIdx.x;
    if (i > n) return;
    if (i == 0) {
        for (int c = 0; c <= pool[0]; ++c) start[c] = 0;
    } else if (i == n) {
        for (int c = pool[n - 1] + 1; c <= nseg; ++c) start[c] = n;
    } else {
        int a = pool[i - 1], b = pool[i];
        for (int c = a + 1; c <= b; ++c) start[c] = i;
    }
}

__global__ void pool_mean(const float* __restrict__ z, const int* __restrict__ start,
                          const int* __restrict__ batch, float* __restrict__ p,
                          int* __restrict__ cnt_out, int* __restrict__ bpool) {
    int c = blockIdx.x, t = threadIdx.x;  // 64 threads
    int s = start[c], e = start[c + 1];
    int cnt = e - s;
    const float4* z4 = (const float4*)z;
    float ax = 0.f, ay = 0.f, az = 0.f, aw = 0.f;
    for (int i = s; i < e; ++i) {
        float4 v = z4[(size_t)i * 64 + t];
        ax += v.x; ay += v.y; az += v.z; aw += v.w;
    }
    float inv = 1.0f / (float)max(cnt, 1);
    ((float4*)p)[(size_t)c * 64 + t] = make_float4(ax * inv, ay * inv, az * inv, aw * inv);
    if (t == 0) {
        cnt_out[c] = cnt;
        int sb = 0;
        for (int i = s; i < e; ++i) sb += batch[i];
        bpool[c] = (int)rintf((float)sb * inv);
    }
}

__global__ void pool_b_accum(const float* __restrict__ z, const int* __restrict__ bpool,
                             float* __restrict__ pb) {
    int c = blockIdx.x, t = threadIdx.x;  // 64 threads
    int b = bpool[c];
#pragma unroll
    for (int j = 0; j < 4; ++j)
        atomicAdd(&pb[b * 256 + t * 4 + j], z[(size_t)c * 256 + t * 4 + j]);
}

__global__ void cntB_accum(const int* __restrict__ bpool, int* __restrict__ cntB, int n) {
    int c = blockIdx.x * blockDim.x + threadIdx.x;
    if (c < n) atomicAdd(&cntB[bpool[c]], 1);
}

// ---------------- heads ----------------

__global__ void head0(const float* __restrict__ xp, const float* __restrict__ linW,
                      const float* __restrict__ linb, const float* __restrict__ xpool1,
                      float* __restrict__ outp, float* __restrict__ xb) {
    int r = blockIdx.x, t = threadIdx.x;  // 64 threads
    __shared__ float xr[256];
    __shared__ float lg[16];
    __shared__ float ex[16];
#pragma unroll
    for (int j = 0; j < 4; ++j) xr[t + 64 * j] = xp[(size_t)r * 256 + t + 64 * j];
    __syncthreads();
    if (t < 16) {
        float acc = linb[t];
        for (int k = 0; k < 256; ++k) acc += xr[k] * linW[k * 16 + t];
        lg[t] = acc;
    }
    __syncthreads();
    if (t < 16) {
        float mx = lg[0];
#pragma unroll
        for (int c = 1; c < 16; ++c) mx = fmaxf(mx, lg[c]);
        ex[t] = expf(lg[t] - mx);
    }
    __syncthreads();
    if (t < 16) {
        float sum = 0.f;
#pragma unroll
        for (int c = 0; c < 16; ++c) sum += ex[c];
        float pv = ex[t] / sum;
        outp[(size_t)r * 16 + t] = pv;
        xb[(size_t)r * 17 + t] = pv;
    }
    if (t == 16) xb[(size_t)r * 17 + 16] = xpool1[r];
}

__global__ void head1(const float* __restrict__ pb, const int* __restrict__ cntB,
                      const float* __restrict__ W, const float* __restrict__ bias,
                      const float* __restrict__ gam, const float* __restrict__ bet,
                      const float* __restrict__ mu, const float* __restrict__ var,
                      const float* __restrict__ linW, const float* __restrict__ linb,
                      float* __restrict__ outp) {
    int b = blockIdx.x, t = threadIdx.x;  // 256 threads
    __shared__ float pr[256];
    __shared__ float yr[256];
    __shared__ float lg[16];
    __shared__ float ex[16];
    int c = cntB[b];
    float inv = 1.0f / (float)max(c, 1);
    pr[t] = pb[b * 256 + t] * inv;
    __syncthreads();
    float acc = bias[t];
    for (int k = 0; k < 256; ++k) acc += pr[k] * W[k * 256 + t];
    float s = gam[t] * rsqrtf(var[t] + EPSc);
    acc = (acc - mu[t]) * s + bet[t];
    if (c == 0) acc = 0.f;
    yr[t] = acc;
    __syncthreads();
    if (t < 16) {
        float l = linb[t];
        for (int k = 0; k < 256; ++k) l += yr[k] * linW[k * 16 + t];
        lg[t] = l;
    }
    __syncthreads();
    if (t < 16) {
        float mx = lg[0];
#pragma unroll
        for (int cc = 1; cc < 16; ++cc) mx = fmaxf(mx, lg[cc]);
        ex[t] = expf(lg[t] - mx);
    }
    __syncthreads();
    if (t < 16) {
        float sum = 0.f;
#pragma unroll
        for (int cc = 0; cc < 16; ++cc) sum += ex[cc];
        outp[48000 + b * 16 + t] = ex[t] / sum;
    }
}

// ---------------- launch ----------------

extern "C" void kernel_launch(void* const* d_in, const int* in_sizes, int n_in,
                              void* d_out, int out_size, void* d_ws, size_t ws_size,
                              hipStream_t stream) {
    const float* x       = (const float*)d_in[0];
    const float* x_pool1 = (const float*)d_in[1];
    const float* W_in0   = (const float*)d_in[2];
    const float* W_h0    = (const float*)d_in[3];
    const float* b0      = (const float*)d_in[4];
    const float* g0      = (const float*)d_in[5];
    const float* be0     = (const float*)d_in[6];
    const float* m0      = (const float*)d_in[7];
    const float* v0      = (const float*)d_in[8];
    const float* W_in1   = (const float*)d_in[9];
    const float* W_h1    = (const float*)d_in[10];
    const float* b1      = (const float*)d_in[11];
    const float* g1      = (const float*)d_in[12];
    const float* be1     = (const float*)d_in[13];
    const float* m1      = (const float*)d_in[14];
    const float* v1      = (const float*)d_in[15];
    const float* linW0   = (const float*)d_in[16];
    const float* linb0   = (const float*)d_in[17];
    const float* linW1   = (const float*)d_in[18];
    const float* linb1   = (const float*)d_in[19];
    const int*   ei      = (const int*)d_in[20];
    const int*   batch   = (const int*)d_in[21];
    const int*   pool1   = (const int*)d_in[22];
    const int*   eip     = (const int*)d_in[23];
    float* outp = (float*)d_out;

    // carve workspace (256B-aligned); zero-init block FIRST (single memset)
    char* p = (char*)d_ws;
    auto carve = [&](size_t bytes) -> void* {
        void* r = (void*)p;
        p += (bytes + 255) & ~(size_t)255;
        return r;
    };
    int*   deg    = (int*)  carve((size_t)NALL * 4);   // zeroed
    int*   tmp    = (int*)  carve((size_t)NALL * 4);   // zeroed
    float* pb     = (float*)carve((size_t)Bc * Hc * 4);// zeroed
    int*   cntB   = (int*)  carve((size_t)Bc * 4);     // zeroed
    size_t zeroBytes = (size_t)((char*)p - (char*)deg);

    int*   rp     = (int*)  carve((size_t)(NALL + 1) * 4);
    float* dinv   = (float*)carve((size_t)NALL * 4);
    int*   blkSum = (int*)  carve(256 * 4);
    int*   blkOff = (int*)  carve(256 * 4);
    unsigned* csw = (unsigned*)carve((size_t)EALL * 4);
    // region1: [xbf | z0bf] aliased later by g1bf (15.36 MB total)
    unsigned short* xbf  = (unsigned short*)carve((size_t)N0c * 256 * 2);
    unsigned short* z0bf = xbf + (size_t)N0c * 128;
    unsigned short* g1bf = xbf;                         // alias (xbf,z0bf dead)
    // region2: [g0bf | z1bf] aliased later by bufA (30.72 MB total)
    unsigned short* g0bf = (unsigned short*)carve((size_t)N0c * 256 * 4);
    unsigned short* z1bf = g0bf + (size_t)N0c * 256;
    float* bufA = (float*)g0bf;                         // alias (g0bf,z1bf dead)

    unsigned short* Wt0 = (unsigned short*)carve((size_t)256 * 128 * 2);
    unsigned short* Wt1 = (unsigned short*)carve((size_t)256 * 256 * 2);
    float* sc0 = (float*)carve(256 * 4);
    float* sh0 = (float*)carve(256 * 4);
    float* sc1 = (float*)carve(256 * 4);
    float* sh1 = (float*)carve(256 * 4);

    int*   start0 = (int*)  carve((size_t)(N1c + 1) * 4);
    int*   cnt0   = (int*)  carve((size_t)N1c * 4);
    float* pmean  = (float*)carve((size_t)N1c * 256 * 4);
    float* xp     = (float*)carve((size_t)N1c * 256 * 4);
    float* xb     = (float*)carve((size_t)N1c * 17 * 4);
    float* zb17   = (float*)carve((size_t)N1c * 17 * 4);
    int*   bpool  = (int*)  carve((size_t)N1c * 4);
    unsigned short* hbbbf = (unsigned short*)carve((size_t)N1c * 256 * 2);
    float* zbb    = (float*)carve((size_t)N1c * 256 * 4);

    hipMemsetAsync(deg, 0, zeroBytes, stream);

    const int* src0 = ei;
    const int* dst0 = ei + E0c;
    const int* src1 = eip;
    const int* dst1 = eip + E1c;

    // ---- unified CSR build ----
    count_deg_all<<<cdiv_i(EALL, 256), 256, 0, stream>>>(dst0, dst1, deg);
    calc_dinv_all<<<cdiv_i(NALL, 256), 256, 0, stream>>>(deg, dinv);
    int nb = cdiv_i(NALL, 256);
    scan_block<<<nb, 256, 0, stream>>>(deg, NALL, rp, blkSum);
    scan_sums<<<1, 256, 0, stream>>>(blkSum, nb, blkOff, rp, NALL);
    scan_add<<<nb, 256, 0, stream>>>(rp, NALL, blkOff);
    fill_csr_all<<<cdiv_i(EALL, 256), 256, 0, stream>>>(src0, dst0, src1, dst1, rp, tmp, dinv, csw);
    cvt_x_bf16<<<cdiv_i(N0c * 32, 256), 256, 0, stream>>>(x, xbf);
    cvt_wt<<<128, 256, 0, stream>>>(W_in0, Wt0, 128);
    cvt_wt<<<256, 256, 0, stream>>>(W_h0, Wt1, 256);
    bn_coef<<<1, 256, 0, stream>>>(b0, g0, be0, m0, v0, sc0, sh0);
    bn_coef<<<1, 256, 0, stream>>>(b0 + Hc, g0 + Hc, be0 + Hc, m0 + Hc, v0 + Hc, sc1, sh1);

    const int*   rp1   = rp + N0c;
    const float* dinv1 = dinv + N0c;

    // ---- phase A: 3 GCN layers on N0 (layers 0/1: bf16 MFMA path) ----
    agg_bf16<16, 2, true><<<2 * cdiv_i(N0c, 4), 256, 0, stream>>>(xbf, rp, csw, dinv, z0bf, N0c);
    gemm_mfma_bn<128><<<cdiv_i(N0c, 64), 256, 0, stream>>>(z0bf, Wt0, sc0, sh0, g0bf, N0c);
    agg_bf16<32, 4, true><<<4 * cdiv_i(N0c, 4), 256, 0, stream>>>(g0bf, rp, csw, dinv, z1bf, N0c);
    gemm_mfma_bn<256><<<cdiv_i(N0c, 64), 256, 0, stream>>>(z1bf, Wt1, sc1, sh1, g1bf, N0c);
    agg_bf16<32, 4, false><<<4 * cdiv_i(N0c, 4), 256, 0, stream>>>(g1bf, rp, csw, dinv, bufA, N0c);

    // layer 2: pool BEFORE GEMM (affine reorder); fp32 vector GEMM (precision)
    seg_starts<<<cdiv_i(N0c + 1, 256), 256, 0, stream>>>(pool1, N0c, N1c, start0);
    pool_mean<<<N1c, 64, 0, stream>>>(bufA, start0, batch, pmean, cnt0, bpool);
    gemm_bn<256, false, true, false><<<dim3(cdiv_i(N1c, 64), 4), 256, 0, stream>>>(
        pmean, W_h0 + Hc * Hc, b0 + 2 * Hc, g0 + 2 * Hc, be0 + 2 * Hc, m0 + 2 * Hc,
        v0 + 2 * Hc, cnt0, xp, N1c);

    // head0: logits + softmax -> d_out[0:48000], xb = [x0 | x_pool1]
    head0<<<N1c, 64, 0, stream>>>(xp, linW0, linb0, x_pool1, outp, xb);

    // ---- phase B: 3 GCN layers on N1 (fp32 vector GEMMs) ----
    agg_small<<<N1c, 64, 0, stream>>>(xb, rp1, csw, dinv1, zb17, 17);
    gemm17_bn_relu<<<N1c, 256, 0, stream>>>(zb17, W_in1, b1, g1, be1, m1, v1, hbbbf);
    agg_bf16<32, 4, false><<<4 * cdiv_i(N1c, 4), 256, 0, stream>>>(hbbbf, rp1, csw, dinv1, zbb, N1c);
    gemm_bn<256, true, false, true><<<dim3(cdiv_i(N1c, 64), 4), 256, 0, stream>>>(
        zbb, W_h1, b1 + Hc, g1 + Hc, be1 + Hc, m1 + Hc, v1 + Hc, nullptr, hbbbf, N1c);
    agg_bf16<32, 4, false><<<4 * cdiv_i(N1c, 4), 256, 0, stream>>>(hbbbf, rp1, csw, dinv1, zbb, N1c);

    // layer 2: pool to B graphs BEFORE GEMM (bpool is NOT sorted -> atomics)
    pool_b_accum<<<N1c, 64, 0, stream>>>(zbb, bpool, pb);
    cntB_accum<<<cdiv_i(N1c, 256), 256, 0, stream>>>(bpool, cntB, N1c);

    // head1: layer2 GEMM+BN + logits + softmax -> d_out[48000:48256]
    head1<<<Bc, 256, 0, stream>>>(pb, cntB, W_h1 + Hc * Hc, b1 + 2 * Hc, g1 + 2 * Hc,
                                  be1 + 2 * Hc, m1 + 2 * Hc, v1 + 2 * Hc, linW1, linb1,
                                  outp);
}

// Round 8
// 547.953 us; speedup vs baseline: 1.5504x; 1.0617x over previous
//
#include <hip/hip_runtime.h>
#include <cstdint>
#include <cstddef>

// Problem constants
#define N0c 30000
#define F0c 128
#define Hc  256
#define Cc  16
#define N1c 3000
#define Bc  16
#define E0c 960000
#define E1c 48000
#define NALL 33000            // N0 + N1 (concatenated graphs)
#define EALL 1008000          // E0 + E1
#define EPSc 1e-5f

static __host__ __device__ inline int cdiv_i(int a, int b) { return (a + b - 1) / b; }

// round-to-nearest-even fp32 -> bf16 (returns the 16 bf16 bits)
static __device__ inline unsigned short bfbits(float f) {
    unsigned u = __float_as_uint(f);
    return (unsigned short)((u + 0x7fffu + ((u >> 16) & 1u)) >> 16);
}

typedef short short8 __attribute__((ext_vector_type(8)));   // 8 bf16 = 4 VGPRs
typedef float floatx4 __attribute__((ext_vector_type(4)));

// ---------------- graph preprocessing (both graphs concatenated) ----------------

__global__ void count_deg_all(const int* __restrict__ dst0, const int* __restrict__ dst1,
                              int* __restrict__ deg) {
    int e = blockIdx.x * blockDim.x + threadIdx.x;
    if (e < E0c) atomicAdd(&deg[dst0[e]], 1);
    else if (e < EALL) atomicAdd(&deg[N0c + dst1[e - E0c]], 1);
}

// scan + dinv fused: dinv[i] = rsqrt(deg[i]+1)
__global__ void scan_block(const int* __restrict__ cnt, int n, int* __restrict__ rp,
                           int* __restrict__ blkSum, float* __restrict__ dinv) {
    __shared__ int sh[256];
    int t = threadIdx.x;
    int i = blockIdx.x * 256 + t;
    int v = (i < n) ? cnt[i] : 0;
    if (i < n) dinv[i] = rsqrtf((float)(v + 1));
    sh[t] = v; __syncthreads();
    for (int off = 1; off < 256; off <<= 1) {
        int add = (t >= off) ? sh[t - off] : 0;
        __syncthreads();
        sh[t] += add;
        __syncthreads();
    }
    if (i < n) rp[i] = sh[t] - v;
    if (t == 255) blkSum[blockIdx.x] = sh[255];
}

__global__ void scan_sums(const int* __restrict__ blkSum, int nb, int* __restrict__ blkOff,
                          int* __restrict__ rp, int n) {
    __shared__ int sh[256];
    int t = threadIdx.x;
    int v = (t < nb) ? blkSum[t] : 0;
    sh[t] = v; __syncthreads();
    for (int off = 1; off < 256; off <<= 1) {
        int add = (t >= off) ? sh[t - off] : 0;
        __syncthreads();
        sh[t] += add;
        __syncthreads();
    }
    blkOff[t] = sh[t] - v;
    if (t == 255) rp[n] = sh[255];
}

__global__ void scan_add(int* __restrict__ rp, int n, const int* __restrict__ blkOff) {
    int i = blockIdx.x * 256 + threadIdx.x;
    if (i < n) rp[i] += blkOff[blockIdx.x];
}

// packed CSR entry: {w_bf16 : high16, src_u16 : low16} -> one 4B load per edge
__global__ void fill_csr_all(const int* __restrict__ src0, const int* __restrict__ dst0,
                             const int* __restrict__ src1, const int* __restrict__ dst1,
                             const int* __restrict__ rp, int* __restrict__ tmp,
                             const float* __restrict__ dinv, unsigned* __restrict__ csw) {
    int e = blockIdx.x * blockDim.x + threadIdx.x;
    if (e >= EALL) return;
    int s, d;
    if (e < E0c) { s = src0[e]; d = dst0[e]; }
    else         { s = N0c + src1[e - E0c]; d = N0c + dst1[e - E0c]; }
    int pos = rp[d] + atomicAdd(&tmp[d], 1);
    float w = dinv[s] * dinv[d];
    int sloc = (e < E0c) ? s : (s - N0c);   // local node id (fits u16)
    csw[pos] = ((unsigned)bfbits(w) << 16) | (unsigned)sloc;
}

// convert x (30000 x 128 fp32) -> bf16
__global__ void cvt_x_bf16(const float* __restrict__ x, unsigned short* __restrict__ xb) {
    int i = blockIdx.x * 256 + threadIdx.x;  // float4 index
    if (i >= N0c * 32) return;
    float4 v = ((const float4*)x)[i];
    ushort4 o;
    o.x = bfbits(v.x); o.y = bfbits(v.y); o.z = bfbits(v.z); o.w = bfbits(v.w);
    ((ushort4*)xb)[i] = o;
}

// fused weight prep: Wt0 = W_in0^T bf16 (blocks 0..127), Wt1 = W_h0[0]^T bf16
// (blocks 128..383), bn coefs layer0 (block 384) / layer1 (block 385)
__global__ void prep_weights(const float* __restrict__ W_in0, const float* __restrict__ W_h0,
                             const float* __restrict__ b0, const float* __restrict__ g0,
                             const float* __restrict__ be0, const float* __restrict__ m0,
                             const float* __restrict__ v0,
                             unsigned short* __restrict__ Wt0, unsigned short* __restrict__ Wt1,
                             float* __restrict__ sc0, float* __restrict__ sh0,
                             float* __restrict__ sc1, float* __restrict__ sh1) {
    int bidx = blockIdx.x, t = threadIdx.x;
    if (bidx < 128) {
        int i = bidx * 256 + t;
        int k = i >> 8, col = i & 255;
        Wt0[col * 128 + k] = bfbits(W_in0[i]);
    } else if (bidx < 384) {
        int i = (bidx - 128) * 256 + t;
        int k = i >> 8, col = i & 255;
        Wt1[col * 256 + k] = bfbits(W_h0[i]);
    } else if (bidx == 384) {
        float s = g0[t] * rsqrtf(v0[t] + EPSc);
        sc0[t] = s;
        sh0[t] = (b0[t] - m0[t]) * s + be0[t];
    } else {
        int tt = t + 256;
        float s = g0[tt] * rsqrtf(v0[tt] + EPSc);
        sc1[t] = s;
        sh1[t] = (b0[tt] - m0[tt]) * s + be0[tt];
    }
}

// ---------------- aggregation (bf16 gather, fp32 accumulate) ----------------

static __device__ inline void acc8(float a[8], float w, uint4 v) {
    a[0] += w * __uint_as_float(v.x << 16);
    a[1] += w * __uint_as_float(v.x & 0xffff0000u);
    a[2] += w * __uint_as_float(v.y << 16);
    a[3] += w * __uint_as_float(v.y & 0xffff0000u);
    a[4] += w * __uint_as_float(v.z << 16);
    a[5] += w * __uint_as_float(v.z & 0xffff0000u);
    a[6] += w * __uint_as_float(v.w << 16);
    a[7] += w * __uint_as_float(v.w & 0xffff0000u);
}

// RSU: bf16 row stride in 16B units (16 for 128-wide, 32 for 256-wide).
// NCHUNK chunks of 64 cols; chunk = blockIdx&(NCHUNK-1) pins chunks to XCD sets.
// Gather addresses are 32-BIT byte offsets (sx<65536, row bytes power-of-two):
// off = (sx << SHIFT) + (c4 << 4) -> v_lshl_add_u32 + s-base load, no 64-bit mul.
template <int RSU, int NCHUNK, bool OBF16>
__global__ __launch_bounds__(256) void agg_bf16(
    const unsigned short* __restrict__ x, const int* __restrict__ rp,
    const unsigned* __restrict__ csw, const float* __restrict__ dinv,
    void* __restrict__ zv, int N) {
    constexpr int SHIFT = (RSU == 32) ? 9 : 8;   // log2(row bytes)
    int b = blockIdx.x;
    int chunk = b & (NCHUNK - 1);
    int node = (b / NCHUNK) * 4 + (threadIdx.x >> 6);
    if (node >= N) return;
    int lane = threadIdx.x & 63;
    int par = lane >> 3;
    int cl = lane & 7;
    int c4 = chunk * 8 + cl;             // uint4 index within bf16 row
    const char* xb = (const char*)x;
    unsigned coff = (unsigned)c4 << 4;   // byte offset of this lane's 16B slice
    float a[8] = {0.f, 0.f, 0.f, 0.f, 0.f, 0.f, 0.f, 0.f};
    if (par == 0) {                      // self-loop term exactly once
        float di = dinv[node];
        uint4 v = *(const uint4*)(xb + (((unsigned)node << SHIFT) + coff));
        acc8(a, di * di, v);
    }
    int e0 = rp[node], e1 = rp[node + 1];
    for (int base = e0; base < e1; base += 64) {
        int avail = e1 - base;
        unsigned my = 0;
        if (lane < avail) my = csw[base + lane];   // 64 edges in ONE load
        int cnt = avail < 64 ? avail : 64;
#pragma unroll
        for (int i = 0; i < 8; ++i) {
            int idx = i * 8 + par;
            unsigned ew = (unsigned)__shfl((int)my, idx, 64);
            if (idx < cnt) {
                unsigned off = ((ew & 0xffffu) << SHIFT) + coff;
                float w = __uint_as_float(ew & 0xffff0000u);
                uint4 v = *(const uint4*)(xb + off);
                acc8(a, w, v);
            }
        }
    }
#pragma unroll
    for (int m = 8; m < 64; m <<= 1) {
#pragma unroll
        for (int k = 0; k < 8; ++k) a[k] += __shfl_xor(a[k], m, 64);
    }
    if (par == 0) {
        if (OBF16) {
            uint4 o;
            o.x = (unsigned)bfbits(a[0]) | ((unsigned)bfbits(a[1]) << 16);
            o.y = (unsigned)bfbits(a[2]) | ((unsigned)bfbits(a[3]) << 16);
            o.z = (unsigned)bfbits(a[4]) | ((unsigned)bfbits(a[5]) << 16);
            o.w = (unsigned)bfbits(a[6]) | ((unsigned)bfbits(a[7]) << 16);
            ((uint4*)zv)[(size_t)node * RSU + c4] = o;
        } else {
            float4* zp = (float4*)zv + (size_t)node * (RSU * 2) + c4 * 2;
            zp[0] = make_float4(a[0], a[1], a[2], a[3]);
            zp[1] = make_float4(a[4], a[5], a[6], a[7]);
        }
    }
}

// ---------------- MFMA bf16 GEMM: (M x K)bf16 @ Wt(256 x K)bf16 -> bf16 out ----
// Block tile 64(M) x 256(N), 256 threads = 4 waves; wave w owns cols [w*64,w*64+64)
// over all 64 rows (4x4 MFMA 16x16x32 subtiles). Epilogue: v*sc+sh, ReLU, bf16.
// LDS stride 40 shorts: b128 accesses land 8 lanes/bank uniformly (= b128 floor).

template <int K>
__global__ __launch_bounds__(256) void gemm_mfma_bn(
    const unsigned short* __restrict__ A, const unsigned short* __restrict__ Wt,
    const float* __restrict__ sc, const float* __restrict__ sh,
    unsigned short* __restrict__ out, int M) {
    constexpr int LDS_S = 40;
    __shared__ unsigned short As[64 * LDS_S];
    __shared__ unsigned short Bs[256 * LDS_S];
    int tid = threadIdx.x;
    int w = tid >> 6, l = tid & 63;
    int quad = l >> 4, lm = l & 15;
    int row0 = blockIdx.x * 64;
    floatx4 acc[4][4];
#pragma unroll
    for (int i = 0; i < 4; ++i)
#pragma unroll
        for (int j = 0; j < 4; ++j) acc[i][j] = (floatx4){0.f, 0.f, 0.f, 0.f};

    int ar = tid >> 2;          // A staging: row 0..63
    int ac = (tid & 3) * 8;     // short offset 0,8,16,24

    for (int k0 = 0; k0 < K; k0 += 32) {
        uint4 av = make_uint4(0, 0, 0, 0);
        if (row0 + ar < M) av = *(const uint4*)(A + (size_t)(row0 + ar) * K + k0 + ac);
        *(uint4*)&As[ar * LDS_S + ac] = av;
#pragma unroll
        for (int c = 0; c < 4; ++c) {    // Bs: thread -> col tid, 4 k-chunks
            uint4 bv = *(const uint4*)(Wt + (size_t)tid * K + k0 + c * 8);
            *(uint4*)&Bs[tid * LDS_S + c * 8] = bv;
        }
        __syncthreads();
        short8 af[4], bf[4];
#pragma unroll
        for (int i = 0; i < 4; ++i)
            af[i] = *(const short8*)&As[(i * 16 + lm) * LDS_S + quad * 8];
#pragma unroll
        for (int j = 0; j < 4; ++j)
            bf[j] = *(const short8*)&Bs[(w * 64 + j * 16 + lm) * LDS_S + quad * 8];
#pragma unroll
        for (int i = 0; i < 4; ++i)
#pragma unroll
            for (int j = 0; j < 4; ++j)
                acc[i][j] = __builtin_amdgcn_mfma_f32_16x16x32_bf16(af[i], bf[j], acc[i][j], 0, 0, 0);
        __syncthreads();
    }
    // epilogue: C/D map col=lane&15, row=quad*4+reg [verified m89/m91]
#pragma unroll
    for (int j = 0; j < 4; ++j) {
        int col = w * 64 + j * 16 + lm;
        float s = sc[col], h = sh[col];
#pragma unroll
        for (int i = 0; i < 4; ++i) {
            int rb = row0 + i * 16 + quad * 4;
#pragma unroll
            for (int r = 0; r < 4; ++r) {
                int row = rb + r;
                if (row < M) {
                    float v = acc[i][j][r] * s + h;
                    v = fmaxf(v, 0.f);
                    out[(size_t)row * 256 + col] = bfbits(v);
                }
            }
        }
    }
}

// ---------------- fp32 vector GEMM (kept for small M=3000, precision-critical) --

template <int K, bool RELU, bool ZEROEMPTY, bool OBF16>
__global__ __launch_bounds__(256) void gemm_bn(
    const float* __restrict__ A, const float* __restrict__ W,
    const float* __restrict__ bias, const float* __restrict__ gam,
    const float* __restrict__ bet, const float* __restrict__ mu,
    const float* __restrict__ var, const int* __restrict__ cnt,
    void* __restrict__ outv, int M) {
    __shared__ __align__(16) float As[16][64];
    __shared__ __align__(16) float Bs[16][64];
    int tid = threadIdx.x;
    int tm = tid >> 4, tn = tid & 15;
    int row0 = blockIdx.x * 64, col0 = blockIdx.y * 64;
    float acc[4][4] = {};
    int ar = tid >> 2;
    int ak = (tid & 3) * 4;
    int bk = tid >> 4;
    int bn = (tid & 15) * 4;

    for (int kk = 0; kk < K; kk += 16) {
        float4 av = make_float4(0.f, 0.f, 0.f, 0.f);
        int grow = row0 + ar;
        if (grow < M) av = *(const float4*)(A + (size_t)grow * K + kk + ak);
        As[ak + 0][ar] = av.x;
        As[ak + 1][ar] = av.y;
        As[ak + 2][ar] = av.z;
        As[ak + 3][ar] = av.w;
        float4 bv = *(const float4*)(W + (size_t)(kk + bk) * 256 + col0 + bn);
        *(float4*)&Bs[bk][bn] = bv;
        __syncthreads();
#pragma unroll
        for (int k = 0; k < 16; ++k) {
            float4 a = *(const float4*)&As[k][tm * 4];
            float4 b = *(const float4*)&Bs[k][tn * 4];
            acc[0][0] += a.x * b.x; acc[0][1] += a.x * b.y; acc[0][2] += a.x * b.z; acc[0][3] += a.x * b.w;
            acc[1][0] += a.y * b.x; acc[1][1] += a.y * b.y; acc[1][2] += a.y * b.z; acc[1][3] += a.y * b.w;
            acc[2][0] += a.z * b.x; acc[2][1] += a.z * b.y; acc[2][2] += a.z * b.z; acc[2][3] += a.z * b.w;
            acc[3][0] += a.w * b.x; acc[3][1] += a.w * b.y; acc[3][2] += a.w * b.z; acc[3][3] += a.w * b.w;
        }
        __syncthreads();
    }
    float bcol[4], scol[4], mcol[4], ecol[4];
#pragma unroll
    for (int j = 0; j < 4; ++j) {
        int col = col0 + tn * 4 + j;
        bcol[j] = bias[col];
        scol[j] = gam[col] * rsqrtf(var[col] + EPSc);
        mcol[j] = mu[col];
        ecol[j] = bet[col];
    }
#pragma unroll
    for (int i = 0; i < 4; ++i) {
        int row = row0 + tm * 4 + i;
        if (row >= M) continue;
        bool zero = false;
        if (ZEROEMPTY) zero = (cnt[row] == 0);
        float r[4];
#pragma unroll
        for (int j = 0; j < 4; ++j) {
            float v = acc[i][j] + bcol[j];
            v = (v - mcol[j]) * scol[j] + ecol[j];
            if (RELU) v = fmaxf(v, 0.f);
            if (zero) v = 0.f;
            r[j] = v;
        }
        if (OBF16) {
            ushort4 o;
            o.x = bfbits(r[0]); o.y = bfbits(r[1]); o.z = bfbits(r[2]); o.w = bfbits(r[3]);
            *(ushort4*)((unsigned short*)outv + (size_t)row * 256 + col0 + tn * 4) = o;
        } else {
            float4 o = make_float4(r[0], r[1], r[2], r[3]);
            *(float4*)((float*)outv + (size_t)row * 256 + col0 + tn * 4) = o;
        }
    }
}

// fused: 17-wide aggregation (graph 1) + K=17 GEMM + BN + ReLU, bf16 out
__global__ void agg17_gemm_bn(const float* __restrict__ xb, const int* __restrict__ rp,
                              const unsigned* __restrict__ csw, const float* __restrict__ dinv,
                              const float* __restrict__ W, const float* __restrict__ bias,
                              const float* __restrict__ gam, const float* __restrict__ bet,
                              const float* __restrict__ mu, const float* __restrict__ var,
                              unsigned short* __restrict__ out) {
    int r = blockIdx.x, t = threadIdx.x;   // 256 threads
    __shared__ float zr[17];
    if (t < 17) {
        float di = dinv[r];
        float acc = di * di * xb[(size_t)r * 17 + t];
        int e0 = rp[r], e1 = rp[r + 1];
        for (int e = e0; e < e1; ++e) {
            unsigned ew = csw[e];
            acc += __uint_as_float(ew & 0xffff0000u) * xb[(size_t)(ew & 0xffffu) * 17 + t];
        }
        zr[t] = acc;
    }
    __syncthreads();
    float acc = bias[t];
#pragma unroll
    for (int k = 0; k < 17; ++k) acc += zr[k] * W[k * 256 + t];
    float s = gam[t] * rsqrtf(var[t] + EPSc);
    acc = (acc - mu[t]) * s + bet[t];
    acc = fmaxf(acc, 0.f);
    out[(size_t)r * 256 + t] = bfbits(acc);
}

// ---------------- pooling ----------------

__global__ void seg_starts(const int* __restrict__ pool, int n, int nseg,
                           int* __restrict__ start) {
    int i = blockIdx.x * blockDim.x + threadIdx.x;
    if (i > n) return;
    if (i == 0) {
        for (int c = 0; c <= pool[0]; ++c) start[c] = 0;
    } else if (i == n) {
        for (int c = pool[n - 1] + 1; c <= nseg; ++c) start[c] = n;
    } else {
        int a = pool[i - 1], b = pool[i];
        for (int c = a + 1; c <= b; ++c) start[c] = i;
    }
}

__global__ void pool_mean(const float* __restrict__ z, const int* __restrict__ start,
                          const int* __restrict__ batch, float* __restrict__ p,
                          int* __restrict__ cnt_out, int* __restrict__ bpool) {
    int c = blockIdx.x, t = threadIdx.x;  // 64 threads
    int s = start[c], e = start[c + 1];
    int cnt = e - s;
    const float4* z4 = (const float4*)z;
    float ax = 0.f, ay = 0.f, az = 0.f, aw = 0.f;
    for (int i = s; i < e; ++i) {
        float4 v = z4[(size_t)i * 64 + t];
        ax += v.x; ay += v.y; az += v.z; aw += v.w;
    }
    float inv = 1.0f / (float)max(cnt, 1);
    ((float4*)p)[(size_t)c * 64 + t] = make_float4(ax * inv, ay * inv, az * inv, aw * inv);
    if (t == 0) {
        cnt_out[c] = cnt;
        int sb = 0;
        for (int i = s; i < e; ++i) sb += batch[i];
        bpool[c] = (int)rintf((float)sb * inv);
    }
}

// fused: scatter-accumulate rows to B graphs + count (t==0)
__global__ void pool_b_accum(const float* __restrict__ z, const int* __restrict__ bpool,
                             float* __restrict__ pb, int* __restrict__ cntB) {
    int c = blockIdx.x, t = threadIdx.x;  // 64 threads
    int b = bpool[c];
#pragma unroll
    for (int j = 0; j < 4; ++j)
        atomicAdd(&pb[b * 256 + t * 4 + j], z[(size_t)c * 256 + t * 4 + j]);
    if (t == 0) atomicAdd(&cntB[b], 1);
}

// ---------------- heads ----------------

__global__ void head0(const float* __restrict__ xp, const float* __restrict__ linW,
                      const float* __restrict__ linb, const float* __restrict__ xpool1,
                      float* __restrict__ outp, float* __restrict__ xb) {
    int r = blockIdx.x, t = threadIdx.x;  // 64 threads
    __shared__ float xr[256];
    __shared__ float lg[16];
    __shared__ float ex[16];
#pragma unroll
    for (int j = 0; j < 4; ++j) xr[t + 64 * j] = xp[(size_t)r * 256 + t + 64 * j];
    __syncthreads();
    if (t < 16) {
        float acc = linb[t];
        for (int k = 0; k < 256; ++k) acc += xr[k] * linW[k * 16 + t];
        lg[t] = acc;
    }
    __syncthreads();
    if (t < 16) {
        float mx = lg[0];
#pragma unroll
        for (int c = 1; c < 16; ++c) mx = fmaxf(mx, lg[c]);
        ex[t] = expf(lg[t] - mx);
    }
    __syncthreads();
    if (t < 16) {
        float sum = 0.f;
#pragma unroll
        for (int c = 0; c < 16; ++c) sum += ex[c];
        float pv = ex[t] / sum;
        outp[(size_t)r * 16 + t] = pv;
        xb[(size_t)r * 17 + t] = pv;
    }
    if (t == 16) xb[(size_t)r * 17 + 16] = xpool1[r];
}

__global__ void head1(const float* __restrict__ pb, const int* __restrict__ cntB,
                      const float* __restrict__ W, const float* __restrict__ bias,
                      const float* __restrict__ gam, const float* __restrict__ bet,
                      const float* __restrict__ mu, const float* __restrict__ var,
                      const float* __restrict__ linW, const float* __restrict__ linb,
                      float* __restrict__ outp) {
    int b = blockIdx.x, t = threadIdx.x;  // 256 threads
    __shared__ float pr[256];
    __shared__ float yr[256];
    __shared__ float lg[16];
    __shared__ float ex[16];
    int c = cntB[b];
    float inv = 1.0f / (float)max(c, 1);
    pr[t] = pb[b * 256 + t] * inv;
    __syncthreads();
    float acc = bias[t];
    for (int k = 0; k < 256; ++k) acc += pr[k] * W[k * 256 + t];
    float s = gam[t] * rsqrtf(var[t] + EPSc);
    acc = (acc - mu[t]) * s + bet[t];
    if (c == 0) acc = 0.f;
    yr[t] = acc;
    __syncthreads();
    if (t < 16) {
        float l = linb[t];
        for (int k = 0; k < 256; ++k) l += yr[k] * linW[k * 16 + t];
        lg[t] = l;
    }
    __syncthreads();
    if (t < 16) {
        float mx = lg[0];
#pragma unroll
        for (int cc = 1; cc < 16; ++cc) mx = fmaxf(mx, lg[cc]);
        ex[t] = expf(lg[t] - mx);
    }
    __syncthreads();
    if (t < 16) {
        float sum = 0.f;
#pragma unroll
        for (int cc = 0; cc < 16; ++cc) sum += ex[cc];
        outp[48000 + b * 16 + t] = ex[t] / sum;
    }
}

// ---------------- launch ----------------

extern "C" void kernel_launch(void* const* d_in, const int* in_sizes, int n_in,
                              void* d_out, int out_size, void* d_ws, size_t ws_size,
                              hipStream_t stream) {
    const float* x       = (const float*)d_in[0];
    const float* x_pool1 = (const float*)d_in[1];
    const float* W_in0   = (const float*)d_in[2];
    const float* W_h0    = (const float*)d_in[3];
    const float* b0      = (const float*)d_in[4];
    const float* g0      = (const float*)d_in[5];
    const float* be0     = (const float*)d_in[6];
    const float* m0      = (const float*)d_in[7];
    const float* v0      = (const float*)d_in[8];
    const float* W_in1   = (const float*)d_in[9];
    const float* W_h1    = (const float*)d_in[10];
    const float* b1      = (const float*)d_in[11];
    const float* g1      = (const float*)d_in[12];
    const float* be1     = (const float*)d_in[13];
    const float* m1      = (const float*)d_in[14];
    const float* v1      = (const float*)d_in[15];
    const float* linW0   = (const float*)d_in[16];
    const float* linb0   = (const float*)d_in[17];
    const float* linW1   = (const float*)d_in[18];
    const float* linb1   = (const float*)d_in[19];
    const int*   ei      = (const int*)d_in[20];
    const int*   batch   = (const int*)d_in[21];
    const int*   pool1   = (const int*)d_in[22];
    const int*   eip     = (const int*)d_in[23];
    float* outp = (float*)d_out;

    // carve workspace (256B-aligned); zero-init block FIRST (single memset)
    char* p = (char*)d_ws;
    auto carve = [&](size_t bytes) -> void* {
        void* r = (void*)p;
        p += (bytes + 255) & ~(size_t)255;
        return r;
    };
    int*   deg    = (int*)  carve((size_t)NALL * 4);   // zeroed
    int*   tmp    = (int*)  carve((size_t)NALL * 4);   // zeroed
    float* pb     = (float*)carve((size_t)Bc * Hc * 4);// zeroed
    int*   cntB   = (int*)  carve((size_t)Bc * 4);     // zeroed
    size_t zeroBytes = (size_t)((char*)p - (char*)deg);

    int*   rp     = (int*)  carve((size_t)(NALL + 1) * 4);
    float* dinv   = (float*)carve((size_t)NALL * 4);
    int*   blkSum = (int*)  carve(256 * 4);
    int*   blkOff = (int*)  carve(256 * 4);
    unsigned* csw = (unsigned*)carve((size_t)EALL * 4);
    // region1: [xbf | z0bf] aliased later by g1bf (15.36 MB total)
    unsigned short* xbf  = (unsigned short*)carve((size_t)N0c * 256 * 2);
    unsigned short* z0bf = xbf + (size_t)N0c * 128;
    unsigned short* g1bf = xbf;                         // alias (xbf,z0bf dead)
    // region2: [g0bf | z1bf] aliased later by bufA (30.72 MB total)
    unsigned short* g0bf = (unsigned short*)carve((size_t)N0c * 256 * 4);
    unsigned short* z1bf = g0bf + (size_t)N0c * 256;
    float* bufA = (float*)g0bf;                         // alias (g0bf,z1bf dead)

    unsigned short* Wt0 = (unsigned short*)carve((size_t)256 * 128 * 2);
    unsigned short* Wt1 = (unsigned short*)carve((size_t)256 * 256 * 2);
    float* sc0 = (float*)carve(256 * 4);
    float* sh0 = (float*)carve(256 * 4);
    float* sc1 = (float*)carve(256 * 4);
    float* sh1 = (float*)carve(256 * 4);

    int*   start0 = (int*)  carve((size_t)(N1c + 1) * 4);
    int*   cnt0   = (int*)  carve((size_t)N1c * 4);
    float* pmean  = (float*)carve((size_t)N1c * 256 * 4);
    float* xp     = (float*)carve((size_t)N1c * 256 * 4);
    float* xb     = (float*)carve((size_t)N1c * 17 * 4);
    int*   bpool  = (int*)  carve((size_t)N1c * 4);
    unsigned short* hbbbf = (unsigned short*)carve((size_t)N1c * 256 * 2);
    float* zbb    = (float*)carve((size_t)N1c * 256 * 4);

    hipMemsetAsync(deg, 0, zeroBytes, stream);

    const int* src0 = ei;
    const int* dst0 = ei + E0c;
    const int* src1 = eip;
    const int* dst1 = eip + E1c;

    // ---- unified CSR build ----
    count_deg_all<<<cdiv_i(EALL, 256), 256, 0, stream>>>(dst0, dst1, deg);
    int nb = cdiv_i(NALL, 256);
    scan_block<<<nb, 256, 0, stream>>>(deg, NALL, rp, blkSum, dinv);
    scan_sums<<<1, 256, 0, stream>>>(blkSum, nb, blkOff, rp, NALL);
    scan_add<<<nb, 256, 0, stream>>>(rp, NALL, blkOff);
    fill_csr_all<<<cdiv_i(EALL, 256), 256, 0, stream>>>(src0, dst0, src1, dst1, rp, tmp, dinv, csw);
    cvt_x_bf16<<<cdiv_i(N0c * 32, 256), 256, 0, stream>>>(x, xbf);
    prep_weights<<<386, 256, 0, stream>>>(W_in0, W_h0, b0, g0, be0, m0, v0,
                                          Wt0, Wt1, sc0, sh0, sc1, sh1);

    const int*   rp1   = rp + N0c;
    const float* dinv1 = dinv + N0c;

    // ---- phase A: 3 GCN layers on N0 (layers 0/1: bf16 MFMA path) ----
    agg_bf16<16, 2, true><<<2 * cdiv_i(N0c, 4), 256, 0, stream>>>(xbf, rp, csw, dinv, z0bf, N0c);
    gemm_mfma_bn<128><<<cdiv_i(N0c, 64), 256, 0, stream>>>(z0bf, Wt0, sc0, sh0, g0bf, N0c);
    agg_bf16<32, 4, true><<<4 * cdiv_i(N0c, 4), 256, 0, stream>>>(g0bf, rp, csw, dinv, z1bf, N0c);
    gemm_mfma_bn<256><<<cdiv_i(N0c, 64), 256, 0, stream>>>(z1bf, Wt1, sc1, sh1, g1bf, N0c);
    agg_bf16<32, 4, false><<<4 * cdiv_i(N0c, 4), 256, 0, stream>>>(g1bf, rp, csw, dinv, bufA, N0c);

    // layer 2: pool BEFORE GEMM (affine reorder); fp32 vector GEMM (precision)
    seg_starts<<<cdiv_i(N0c + 1, 256), 256, 0, stream>>>(pool1, N0c, N1c, start0);
    pool_mean<<<N1c, 64, 0, stream>>>(bufA, start0, batch, pmean, cnt0, bpool);
    gemm_bn<256, false, true, false><<<dim3(cdiv_i(N1c, 64), 4), 256, 0, stream>>>(
        pmean, W_h0 + Hc * Hc, b0 + 2 * Hc, g0 + 2 * Hc, be0 + 2 * Hc, m0 + 2 * Hc,
        v0 + 2 * Hc, cnt0, xp, N1c);

    // head0: logits + softmax -> d_out[0:48000], xb = [x0 | x_pool1]
    head0<<<N1c, 64, 0, stream>>>(xp, linW0, linb0, x_pool1, outp, xb);

    // ---- phase B: 3 GCN layers on N1 (fp32 vector GEMMs) ----
    agg17_gemm_bn<<<N1c, 256, 0, stream>>>(xb, rp1, csw, dinv1, W_in1, b1, g1, be1,
                                           m1, v1, hbbbf);
    agg_bf16<32, 4, false><<<4 * cdiv_i(N1c, 4), 256, 0, stream>>>(hbbbf, rp1, csw, dinv1, zbb, N1c);
    gemm_bn<256, true, false, true><<<dim3(cdiv_i(N1c, 64), 4), 256, 0, stream>>>(
        zbb, W_h1, b1 + Hc, g1 + Hc, be1 + Hc, m1 + Hc, v1 + Hc, nullptr, hbbbf, N1c);
    agg_bf16<32, 4, false><<<4 * cdiv_i(N1c, 4), 256, 0, stream>>>(hbbbf, rp1, csw, dinv1, zbb, N1c);

    // layer 2: pool to B graphs BEFORE GEMM (bpool is NOT sorted -> atomics)
    pool_b_accum<<<N1c, 64, 0, stream>>>(zbb, bpool, pb, cntB);

    // head1: layer2 GEMM+BN + logits + softmax -> d_out[48000:48256]
    head1<<<Bc, 256, 0, stream>>>(pb, cntB, W_h1 + Hc * Hc, b1 + 2 * Hc, g1 + 2 * Hc,
                                  be1 + 2 * Hc, m1 + 2 * Hc, v1 + 2 * Hc, linW1, linb1,
                                  outp);
}

// Round 9
// 545.131 us; speedup vs baseline: 1.5584x; 1.0052x over previous
//
#include <hip/hip_runtime.h>
#include <cstdint>
#include <cstddef>

// Problem constants
#define N0c 30000
#define F0c 128
#define Hc  256
#define Cc  16
#define N1c 3000
#define Bc  16
#define E0c 960000
#define E1c 48000
#define NALL 33000            // N0 + N1 (concatenated graphs)
#define EALL 1008000          // E0 + E1
#define EPSc 1e-5f

static __host__ __device__ inline int cdiv_i(int a, int b) { return (a + b - 1) / b; }

// round-to-nearest-even fp32 -> bf16 (returns the 16 bf16 bits)
static __device__ inline unsigned short bfbits(float f) {
    unsigned u = __float_as_uint(f);
    return (unsigned short)((u + 0x7fffu + ((u >> 16) & 1u)) >> 16);
}

typedef short short8 __attribute__((ext_vector_type(8)));   // 8 bf16 = 4 VGPRs
typedef float floatx4 __attribute__((ext_vector_type(4)));

// ---------------- graph preprocessing (both graphs concatenated) ----------------

__global__ void count_deg_all(const int* __restrict__ dst0, const int* __restrict__ dst1,
                              int* __restrict__ deg) {
    int e = blockIdx.x * blockDim.x + threadIdx.x;
    if (e < E0c) atomicAdd(&deg[dst0[e]], 1);
    else if (e < EALL) atomicAdd(&deg[N0c + dst1[e - E0c]], 1);
}

// scan + dinv fused: dinv[i] = rsqrt(deg[i]+1)
__global__ void scan_block(const int* __restrict__ cnt, int n, int* __restrict__ rp,
                           int* __restrict__ blkSum, float* __restrict__ dinv) {
    __shared__ int sh[256];
    int t = threadIdx.x;
    int i = blockIdx.x * 256 + t;
    int v = (i < n) ? cnt[i] : 0;
    if (i < n) dinv[i] = rsqrtf((float)(v + 1));
    sh[t] = v; __syncthreads();
    for (int off = 1; off < 256; off <<= 1) {
        int add = (t >= off) ? sh[t - off] : 0;
        __syncthreads();
        sh[t] += add;
        __syncthreads();
    }
    if (i < n) rp[i] = sh[t] - v;
    if (t == 255) blkSum[blockIdx.x] = sh[255];
}

__global__ void scan_sums(const int* __restrict__ blkSum, int nb, int* __restrict__ blkOff,
                          int* __restrict__ rp, int n) {
    __shared__ int sh[256];
    int t = threadIdx.x;
    int v = (t < nb) ? blkSum[t] : 0;
    sh[t] = v; __syncthreads();
    for (int off = 1; off < 256; off <<= 1) {
        int add = (t >= off) ? sh[t - off] : 0;
        __syncthreads();
        sh[t] += add;
        __syncthreads();
    }
    blkOff[t] = sh[t] - v;
    if (t == 255) rp[n] = sh[255];
}

__global__ void scan_add(int* __restrict__ rp, int n, const int* __restrict__ blkOff) {
    int i = blockIdx.x * 256 + threadIdx.x;
    if (i < n) rp[i] += blkOff[blockIdx.x];
}

// packed CSR entry: {w_bf16 : high16, src_u16 : low16} -> one 4B load per edge
__global__ void fill_csr_all(const int* __restrict__ src0, const int* __restrict__ dst0,
                             const int* __restrict__ src1, const int* __restrict__ dst1,
                             const int* __restrict__ rp, int* __restrict__ tmp,
                             const float* __restrict__ dinv, unsigned* __restrict__ csw) {
    int e = blockIdx.x * blockDim.x + threadIdx.x;
    if (e >= EALL) return;
    int s, d;
    if (e < E0c) { s = src0[e]; d = dst0[e]; }
    else         { s = N0c + src1[e - E0c]; d = N0c + dst1[e - E0c]; }
    int pos = rp[d] + atomicAdd(&tmp[d], 1);
    float w = dinv[s] * dinv[d];
    int sloc = (e < E0c) ? s : (s - N0c);   // local node id (fits u16)
    csw[pos] = ((unsigned)bfbits(w) << 16) | (unsigned)sloc;
}

// convert x (30000 x 128 fp32) -> bf16
__global__ void cvt_x_bf16(const float* __restrict__ x, unsigned short* __restrict__ xb) {
    int i = blockIdx.x * 256 + threadIdx.x;  // float4 index
    if (i >= N0c * 32) return;
    float4 v = ((const float4*)x)[i];
    ushort4 o;
    o.x = bfbits(v.x); o.y = bfbits(v.y); o.z = bfbits(v.z); o.w = bfbits(v.w);
    ((ushort4*)xb)[i] = o;
}

// fused weight prep: Wt0 = W_in0^T bf16 (blocks 0..127), Wt1 = W_h0[0]^T bf16
// (blocks 128..383), bn coefs layer0 (block 384) / layer1 (block 385)
__global__ void prep_weights(const float* __restrict__ W_in0, const float* __restrict__ W_h0,
                             const float* __restrict__ b0, const float* __restrict__ g0,
                             const float* __restrict__ be0, const float* __restrict__ m0,
                             const float* __restrict__ v0,
                             unsigned short* __restrict__ Wt0, unsigned short* __restrict__ Wt1,
                             float* __restrict__ sc0, float* __restrict__ sh0,
                             float* __restrict__ sc1, float* __restrict__ sh1) {
    int bidx = blockIdx.x, t = threadIdx.x;
    if (bidx < 128) {
        int i = bidx * 256 + t;
        int k = i >> 8, col = i & 255;
        Wt0[col * 128 + k] = bfbits(W_in0[i]);
    } else if (bidx < 384) {
        int i = (bidx - 128) * 256 + t;
        int k = i >> 8, col = i & 255;
        Wt1[col * 256 + k] = bfbits(W_h0[i]);
    } else if (bidx == 384) {
        float s = g0[t] * rsqrtf(v0[t] + EPSc);
        sc0[t] = s;
        sh0[t] = (b0[t] - m0[t]) * s + be0[t];
    } else {
        int tt = t + 256;
        float s = g0[tt] * rsqrtf(v0[tt] + EPSc);
        sc1[t] = s;
        sh1[t] = (b0[tt] - m0[tt]) * s + be0[tt];
    }
}

// ---------------- aggregation (bf16 gather, fp32 accumulate) ----------------

static __device__ inline void acc8(float a[8], float w, uint4 v) {
    a[0] += w * __uint_as_float(v.x << 16);
    a[1] += w * __uint_as_float(v.x & 0xffff0000u);
    a[2] += w * __uint_as_float(v.y << 16);
    a[3] += w * __uint_as_float(v.y & 0xffff0000u);
    a[4] += w * __uint_as_float(v.z << 16);
    a[5] += w * __uint_as_float(v.z & 0xffff0000u);
    a[6] += w * __uint_as_float(v.w << 16);
    a[7] += w * __uint_as_float(v.w & 0xffff0000u);
}

// RSU: bf16 row stride in 16B units (16 for 128-wide, 32 for 256-wide).
// NCHUNK chunks of 64 cols; chunk = blockIdx&(NCHUNK-1) pins chunks to XCD sets.
// Gather addresses are 32-BIT byte offsets (sx<65536, rows power-of-two bytes).
// KEY (r9): deg is wave-uniform -> loop trip count (deg>>3) is a SCALAR bound;
// dead unroll steps (mean deg 32 vs 64 slots) no longer issue their ~20 VALU
// instrs under exec-mask. Tail step handles deg%8 with a single guarded step.
template <int RSU, int NCHUNK, bool OBF16>
__global__ __launch_bounds__(256) void agg_bf16(
    const unsigned short* __restrict__ x, const int* __restrict__ rp,
    const unsigned* __restrict__ csw, const float* __restrict__ dinv,
    void* __restrict__ zv, int N) {
    constexpr int SHIFT = (RSU == 32) ? 9 : 8;   // log2(row bytes)
    int b = blockIdx.x;
    int chunk = b & (NCHUNK - 1);
    int node = (b / NCHUNK) * 4 + (threadIdx.x >> 6);
    if (node >= N) return;
    int lane = threadIdx.x & 63;
    int par = lane >> 3;
    int cl = lane & 7;
    int c4 = chunk * 8 + cl;             // uint4 index within bf16 row
    const char* xb = (const char*)x;
    unsigned coff = (unsigned)c4 << 4;   // byte offset of this lane's 16B slice
    float a[8] = {0.f, 0.f, 0.f, 0.f, 0.f, 0.f, 0.f, 0.f};
    if (par == 0) {                      // self-loop term exactly once
        float di = dinv[node];
        uint4 v = *(const uint4*)(xb + (((unsigned)node << SHIFT) + coff));
        acc8(a, di * di, v);
    }
    int e0 = rp[node], e1 = rp[node + 1];
    for (int base = e0; base < e1; base += 64) {
        int batch = e1 - base;
        if (batch > 64) batch = 64;
        unsigned my = 0;
        if (lane < batch) my = csw[base + lane];   // up to 64 edges in ONE load
        int full = batch >> 3;                      // wave-uniform trip count
        for (int i = 0; i < full; ++i) {
            unsigned ew = (unsigned)__shfl((int)my, i * 8 + par, 64);
            unsigned off = ((ew & 0xffffu) << SHIFT) + coff;
            float w = __uint_as_float(ew & 0xffff0000u);
            uint4 v = *(const uint4*)(xb + off);
            acc8(a, w, v);
        }
        int rem = batch & 7;
        if (rem) {                                  // single guarded tail step
            unsigned ew = (unsigned)__shfl((int)my, full * 8 + par, 64);
            if (par < rem) {
                unsigned off = ((ew & 0xffffu) << SHIFT) + coff;
                float w = __uint_as_float(ew & 0xffff0000u);
                uint4 v = *(const uint4*)(xb + off);
                acc8(a, w, v);
            }
        }
    }
#pragma unroll
    for (int m = 8; m < 64; m <<= 1) {
#pragma unroll
        for (int k = 0; k < 8; ++k) a[k] += __shfl_xor(a[k], m, 64);
    }
    if (par == 0) {
        if (OBF16) {
            uint4 o;
            o.x = (unsigned)bfbits(a[0]) | ((unsigned)bfbits(a[1]) << 16);
            o.y = (unsigned)bfbits(a[2]) | ((unsigned)bfbits(a[3]) << 16);
            o.z = (unsigned)bfbits(a[4]) | ((unsigned)bfbits(a[5]) << 16);
            o.w = (unsigned)bfbits(a[6]) | ((unsigned)bfbits(a[7]) << 16);
            ((uint4*)zv)[(size_t)node * RSU + c4] = o;
        } else {
            float4* zp = (float4*)zv + (size_t)node * (RSU * 2) + c4 * 2;
            zp[0] = make_float4(a[0], a[1], a[2], a[3]);
            zp[1] = make_float4(a[4], a[5], a[6], a[7]);
        }
    }
}

// ---------------- MFMA bf16 GEMM: (M x K)bf16 @ Wt(256 x K)bf16 -> bf16 out ----
// Block tile 64(M) x 256(N), 256 threads = 4 waves; wave w owns cols [w*64,w*64+64)
// over all 64 rows (4x4 MFMA 16x16x32 subtiles). Epilogue: v*sc+sh, ReLU, bf16.
// LDS stride 40 shorts: b128 accesses land 8 lanes/bank uniformly (= b128 floor).

template <int K>
__global__ __launch_bounds__(256) void gemm_mfma_bn(
    const unsigned short* __restrict__ A, const unsigned short* __restrict__ Wt,
    const float* __restrict__ sc, const float* __restrict__ sh,
    unsigned short* __restrict__ out, int M) {
    constexpr int LDS_S = 40;
    __shared__ unsigned short As[64 * LDS_S];
    __shared__ unsigned short Bs[256 * LDS_S];
    int tid = threadIdx.x;
    int w = tid >> 6, l = tid & 63;
    int quad = l >> 4, lm = l & 15;
    int row0 = blockIdx.x * 64;
    floatx4 acc[4][4];
#pragma unroll
    for (int i = 0; i < 4; ++i)
#pragma unroll
        for (int j = 0; j < 4; ++j) acc[i][j] = (floatx4){0.f, 0.f, 0.f, 0.f};

    int ar = tid >> 2;          // A staging: row 0..63
    int ac = (tid & 3) * 8;     // short offset 0,8,16,24

    for (int k0 = 0; k0 < K; k0 += 32) {
        uint4 av = make_uint4(0, 0, 0, 0);
        if (row0 + ar < M) av = *(const uint4*)(A + (size_t)(row0 + ar) * K + k0 + ac);
        *(uint4*)&As[ar * LDS_S + ac] = av;
#pragma unroll
        for (int c = 0; c < 4; ++c) {    // Bs: thread -> col tid, 4 k-chunks
            uint4 bv = *(const uint4*)(Wt + (size_t)tid * K + k0 + c * 8);
            *(uint4*)&Bs[tid * LDS_S + c * 8] = bv;
        }
        __syncthreads();
        short8 af[4], bf[4];
#pragma unroll
        for (int i = 0; i < 4; ++i)
            af[i] = *(const short8*)&As[(i * 16 + lm) * LDS_S + quad * 8];
#pragma unroll
        for (int j = 0; j < 4; ++j)
            bf[j] = *(const short8*)&Bs[(w * 64 + j * 16 + lm) * LDS_S + quad * 8];
#pragma unroll
        for (int i = 0; i < 4; ++i)
#pragma unroll
            for (int j = 0; j < 4; ++j)
                acc[i][j] = __builtin_amdgcn_mfma_f32_16x16x32_bf16(af[i], bf[j], acc[i][j], 0, 0, 0);
        __syncthreads();
    }
    // epilogue: C/D map col=lane&15, row=quad*4+reg [verified m89/m91]
#pragma unroll
    for (int j = 0; j < 4; ++j) {
        int col = w * 64 + j * 16 + lm;
        float s = sc[col], h = sh[col];
#pragma unroll
        for (int i = 0; i < 4; ++i) {
            int rb = row0 + i * 16 + quad * 4;
#pragma unroll
            for (int r = 0; r < 4; ++r) {
                int row = rb + r;
                if (row < M) {
                    float v = acc[i][j][r] * s + h;
                    v = fmaxf(v, 0.f);
                    out[(size_t)row * 256 + col] = bfbits(v);
                }
            }
        }
    }
}

// ---------------- fp32 vector GEMM (kept for small M=3000, precision-critical) --

template <int K, bool RELU, bool ZEROEMPTY, bool OBF16>
__global__ __launch_bounds__(256) void gemm_bn(
    const float* __restrict__ A, const float* __restrict__ W,
    const float* __restrict__ bias, const float* __restrict__ gam,
    const float* __restrict__ bet, const float* __restrict__ mu,
    const float* __restrict__ var, const int* __restrict__ cnt,
    void* __restrict__ outv, int M) {
    __shared__ __align__(16) float As[16][64];
    __shared__ __align__(16) float Bs[16][64];
    int tid = threadIdx.x;
    int tm = tid >> 4, tn = tid & 15;
    int row0 = blockIdx.x * 64, col0 = blockIdx.y * 64;
    float acc[4][4] = {};
    int ar = tid >> 2;
    int ak = (tid & 3) * 4;
    int bk = tid >> 4;
    int bn = (tid & 15) * 4;

    for (int kk = 0; kk < K; kk += 16) {
        float4 av = make_float4(0.f, 0.f, 0.f, 0.f);
        int grow = row0 + ar;
        if (grow < M) av = *(const float4*)(A + (size_t)grow * K + kk + ak);
        As[ak + 0][ar] = av.x;
        As[ak + 1][ar] = av.y;
        As[ak + 2][ar] = av.z;
        As[ak + 3][ar] = av.w;
        float4 bv = *(const float4*)(W + (size_t)(kk + bk) * 256 + col0 + bn);
        *(float4*)&Bs[bk][bn] = bv;
        __syncthreads();
#pragma unroll
        for (int k = 0; k < 16; ++k) {
            float4 a = *(const float4*)&As[k][tm * 4];
            float4 b = *(const float4*)&Bs[k][tn * 4];
            acc[0][0] += a.x * b.x; acc[0][1] += a.x * b.y; acc[0][2] += a.x * b.z; acc[0][3] += a.x * b.w;
            acc[1][0] += a.y * b.x; acc[1][1] += a.y * b.y; acc[1][2] += a.y * b.z; acc[1][3] += a.y * b.w;
            acc[2][0] += a.z * b.x; acc[2][1] += a.z * b.y; acc[2][2] += a.z * b.z; acc[2][3] += a.z * b.w;
            acc[3][0] += a.w * b.x; acc[3][1] += a.w * b.y; acc[3][2] += a.w * b.z; acc[3][3] += a.w * b.w;
        }
        __syncthreads();
    }
    float bcol[4], scol[4], mcol[4], ecol[4];
#pragma unroll
    for (int j = 0; j < 4; ++j) {
        int col = col0 + tn * 4 + j;
        bcol[j] = bias[col];
        scol[j] = gam[col] * rsqrtf(var[col] + EPSc);
        mcol[j] = mu[col];
        ecol[j] = bet[col];
    }
#pragma unroll
    for (int i = 0; i < 4; ++i) {
        int row = row0 + tm * 4 + i;
        if (row >= M) continue;
        bool zero = false;
        if (ZEROEMPTY) zero = (cnt[row] == 0);
        float r[4];
#pragma unroll
        for (int j = 0; j < 4; ++j) {
            float v = acc[i][j] + bcol[j];
            v = (v - mcol[j]) * scol[j] + ecol[j];
            if (RELU) v = fmaxf(v, 0.f);
            if (zero) v = 0.f;
            r[j] = v;
        }
        if (OBF16) {
            ushort4 o;
            o.x = bfbits(r[0]); o.y = bfbits(r[1]); o.z = bfbits(r[2]); o.w = bfbits(r[3]);
            *(ushort4*)((unsigned short*)outv + (size_t)row * 256 + col0 + tn * 4) = o;
        } else {
            float4 o = make_float4(r[0], r[1], r[2], r[3]);
            *(float4*)((float*)outv + (size_t)row * 256 + col0 + tn * 4) = o;
        }
    }
}

// fused: 17-wide aggregation (graph 1) + K=17 GEMM + BN + ReLU, bf16 out
__global__ void agg17_gemm_bn(const float* __restrict__ xb, const int* __restrict__ rp,
                              const unsigned* __restrict__ csw, const float* __restrict__ dinv,
                              const float* __restrict__ W, const float* __restrict__ bias,
                              const float* __restrict__ gam, const float* __restrict__ bet,
                              const float* __restrict__ mu, const float* __restrict__ var,
                              unsigned short* __restrict__ out) {
    int r = blockIdx.x, t = threadIdx.x;   // 256 threads
    __shared__ float zr[17];
    if (t < 17) {
        float di = dinv[r];
        float acc = di * di * xb[(size_t)r * 17 + t];
        int e0 = rp[r], e1 = rp[r + 1];
        for (int e = e0; e < e1; ++e) {
            unsigned ew = csw[e];
            acc += __uint_as_float(ew & 0xffff0000u) * xb[(size_t)(ew & 0xffffu) * 17 + t];
        }
        zr[t] = acc;
    }
    __syncthreads();
    float acc = bias[t];
#pragma unroll
    for (int k = 0; k < 17; ++k) acc += zr[k] * W[k * 256 + t];
    float s = gam[t] * rsqrtf(var[t] + EPSc);
    acc = (acc - mu[t]) * s + bet[t];
    acc = fmaxf(acc, 0.f);
    out[(size_t)r * 256 + t] = bfbits(acc);
}

// ---------------- pooling ----------------

__global__ void seg_starts(const int* __restrict__ pool, int n, int nseg,
                           int* __restrict__ start) {
    int i = blockIdx.x * blockDim.x + threadIdx.x;
    if (i > n) return;
    if (i == 0) {
        for (int c = 0; c <= pool[0]; ++c) start[c] = 0;
    } else if (i == n) {
        for (int c = pool[n - 1] + 1; c <= nseg; ++c) start[c] = n;
    } else {
        int a = pool[i - 1], b = pool[i];
        for (int c = a + 1; c <= b; ++c) start[c] = i;
    }
}

__global__ void pool_mean(const float* __restrict__ z, const int* __restrict__ start,
                          const int* __restrict__ batch, float* __restrict__ p,
                          int* __restrict__ cnt_out, int* __restrict__ bpool) {
    int c = blockIdx.x, t = threadIdx.x;  // 64 threads
    int s = start[c], e = start[c + 1];
    int cnt = e - s;
    const float4* z4 = (const float4*)z;
    float ax = 0.f, ay = 0.f, az = 0.f, aw = 0.f;
    for (int i = s; i < e; ++i) {
        float4 v = z4[(size_t)i * 64 + t];
        ax += v.x; ay += v.y; az += v.z; aw += v.w;
    }
    float inv = 1.0f / (float)max(cnt, 1);
    ((float4*)p)[(size_t)c * 64 + t] = make_float4(ax * inv, ay * inv, az * inv, aw * inv);
    if (t == 0) {
        cnt_out[c] = cnt;
        int sb = 0;
        for (int i = s; i < e; ++i) sb += batch[i];
        bpool[c] = (int)rintf((float)sb * inv);
    }
}

// fused: scatter-accumulate rows to B graphs + count (t==0)
__global__ void pool_b_accum(const float* __restrict__ z, const int* __restrict__ bpool,
                             float* __restrict__ pb, int* __restrict__ cntB) {
    int c = blockIdx.x, t = threadIdx.x;  // 64 threads
    int b = bpool[c];
#pragma unroll
    for (int j = 0; j < 4; ++j)
        atomicAdd(&pb[b * 256 + t * 4 + j], z[(size_t)c * 256 + t * 4 + j]);
    if (t == 0) atomicAdd(&cntB[b], 1);
}

// ---------------- heads ----------------

__global__ void head0(const float* __restrict__ xp, const float* __restrict__ linW,
                      const float* __restrict__ linb, const float* __restrict__ xpool1,
                      float* __restrict__ outp, float* __restrict__ xb) {
    int r = blockIdx.x, t = threadIdx.x;  // 64 threads
    __shared__ float xr[256];
    __shared__ float lg[16];
    __shared__ float ex[16];
#pragma unroll
    for (int j = 0; j < 4; ++j) xr[t + 64 * j] = xp[(size_t)r * 256 + t + 64 * j];
    __syncthreads();
    if (t < 16) {
        float acc = linb[t];
        for (int k = 0; k < 256; ++k) acc += xr[k] * linW[k * 16 + t];
        lg[t] = acc;
    }
    __syncthreads();
    if (t < 16) {
        float mx = lg[0];
#pragma unroll
        for (int c = 1; c < 16; ++c) mx = fmaxf(mx, lg[c]);
        ex[t] = expf(lg[t] - mx);
    }
    __syncthreads();
    if (t < 16) {
        float sum = 0.f;
#pragma unroll
        for (int c = 0; c < 16; ++c) sum += ex[c];
        float pv = ex[t] / sum;
        outp[(size_t)r * 16 + t] = pv;
        xb[(size_t)r * 17 + t] = pv;
    }
    if (t == 16) xb[(size_t)r * 17 + 16] = xpool1[r];
}

__global__ void head1(const float* __restrict__ pb, const int* __restrict__ cntB,
                      const float* __restrict__ W, const float* __restrict__ bias,
                      const float* __restrict__ gam, const float* __restrict__ bet,
                      const float* __restrict__ mu, const float* __restrict__ var,
                      const float* __restrict__ linW, const float* __restrict__ linb,
                      float* __restrict__ outp) {
    int b = blockIdx.x, t = threadIdx.x;  // 256 threads
    __shared__ float pr[256];
    __shared__ float yr[256];
    __shared__ float lg[16];
    __shared__ float ex[16];
    int c = cntB[b];
    float inv = 1.0f / (float)max(c, 1);
    pr[t] = pb[b * 256 + t] * inv;
    __syncthreads();
    float acc = bias[t];
    for (int k = 0; k < 256; ++k) acc += pr[k] * W[k * 256 + t];
    float s = gam[t] * rsqrtf(var[t] + EPSc);
    acc = (acc - mu[t]) * s + bet[t];
    if (c == 0) acc = 0.f;
    yr[t] = acc;
    __syncthreads();
    if (t < 16) {
        float l = linb[t];
        for (int k = 0; k < 256; ++k) l += yr[k] * linW[k * 16 + t];
        lg[t] = l;
    }
    __syncthreads();
    if (t < 16) {
        float mx = lg[0];
#pragma unroll
        for (int cc = 1; cc < 16; ++cc) mx = fmaxf(mx, lg[cc]);
        ex[t] = expf(lg[t] - mx);
    }
    __syncthreads();
    if (t < 16) {
        float sum = 0.f;
#pragma unroll
        for (int cc = 0; cc < 16; ++cc) sum += ex[cc];
        outp[48000 + b * 16 + t] = ex[t] / sum;
    }
}

// ---------------- launch ----------------

extern "C" void kernel_launch(void* const* d_in, const int* in_sizes, int n_in,
                              void* d_out, int out_size, void* d_ws, size_t ws_size,
                              hipStream_t stream) {
    const float* x       = (const float*)d_in[0];
    const float* x_pool1 = (const float*)d_in[1];
    const float* W_in0   = (const float*)d_in[2];
    const float* W_h0    = (const float*)d_in[3];
    const float* b0      = (const float*)d_in[4];
    const float* g0      = (const float*)d_in[5];
    const float* be0     = (const float*)d_in[6];
    const float* m0      = (const float*)d_in[7];
    const float* v0      = (const float*)d_in[8];
    const float* W_in1   = (const float*)d_in[9];
    const float* W_h1    = (const float*)d_in[10];
    const float* b1      = (const float*)d_in[11];
    const float* g1      = (const float*)d_in[12];
    const float* be1     = (const float*)d_in[13];
    const float* m1      = (const float*)d_in[14];
    const float* v1      = (const float*)d_in[15];
    const float* linW0   = (const float*)d_in[16];
    const float* linb0   = (const float*)d_in[17];
    const float* linW1   = (const float*)d_in[18];
    const float* linb1   = (const float*)d_in[19];
    const int*   ei      = (const int*)d_in[20];
    const int*   batch   = (const int*)d_in[21];
    const int*   pool1   = (const int*)d_in[22];
    const int*   eip     = (const int*)d_in[23];
    float* outp = (float*)d_out;

    // carve workspace (256B-aligned); zero-init block FIRST (single memset)
    char* p = (char*)d_ws;
    auto carve = [&](size_t bytes) -> void* {
        void* r = (void*)p;
        p += (bytes + 255) & ~(size_t)255;
        return r;
    };
    int*   deg    = (int*)  carve((size_t)NALL * 4);   // zeroed
    int*   tmp    = (int*)  carve((size_t)NALL * 4);   // zeroed
    float* pb     = (float*)carve((size_t)Bc * Hc * 4);// zeroed
    int*   cntB   = (int*)  carve((size_t)Bc * 4);     // zeroed
    size_t zeroBytes = (size_t)((char*)p - (char*)deg);

    int*   rp     = (int*)  carve((size_t)(NALL + 1) * 4);
    float* dinv   = (float*)carve((size_t)NALL * 4);
    int*   blkSum = (int*)  carve(256 * 4);
    int*   blkOff = (int*)  carve(256 * 4);
    unsigned* csw = (unsigned*)carve((size_t)EALL * 4);
    // region1: [xbf | z0bf] aliased later by g1bf (15.36 MB total)
    unsigned short* xbf  = (unsigned short*)carve((size_t)N0c * 256 * 2);
    unsigned short* z0bf = xbf + (size_t)N0c * 128;
    unsigned short* g1bf = xbf;                         // alias (xbf,z0bf dead)
    // region2: [g0bf | z1bf] aliased later by bufA (30.72 MB total)
    unsigned short* g0bf = (unsigned short*)carve((size_t)N0c * 256 * 4);
    unsigned short* z1bf = g0bf + (size_t)N0c * 256;
    float* bufA = (float*)g0bf;                         // alias (g0bf,z1bf dead)

    unsigned short* Wt0 = (unsigned short*)carve((size_t)256 * 128 * 2);
    unsigned short* Wt1 = (unsigned short*)carve((size_t)256 * 256 * 2);
    float* sc0 = (float*)carve(256 * 4);
    float* sh0 = (float*)carve(256 * 4);
    float* sc1 = (float*)carve(256 * 4);
    float* sh1 = (float*)carve(256 * 4);

    int*   start0 = (int*)  carve((size_t)(N1c + 1) * 4);
    int*   cnt0   = (int*)  carve((size_t)N1c * 4);
    float* pmean  = (float*)carve((size_t)N1c * 256 * 4);
    float* xp     = (float*)carve((size_t)N1c * 256 * 4);
    float* xb     = (float*)carve((size_t)N1c * 17 * 4);
    int*   bpool  = (int*)  carve((size_t)N1c * 4);
    unsigned short* hbbbf = (unsigned short*)carve((size_t)N1c * 256 * 2);
    float* zbb    = (float*)carve((size_t)N1c * 256 * 4);

    hipMemsetAsync(deg, 0, zeroBytes, stream);

    const int* src0 = ei;
    const int* dst0 = ei + E0c;
    const int* src1 = eip;
    const int* dst1 = eip + E1c;

    // ---- unified CSR build ----
    count_deg_all<<<cdiv_i(EALL, 256), 256, 0, stream>>>(dst0, dst1, deg);
    int nb = cdiv_i(NALL, 256);
    scan_block<<<nb, 256, 0, stream>>>(deg, NALL, rp, blkSum, dinv);
    scan_sums<<<1, 256, 0, stream>>>(blkSum, nb, blkOff, rp, NALL);
    scan_add<<<nb, 256, 0, stream>>>(rp, NALL, blkOff);
    fill_csr_all<<<cdiv_i(EALL, 256), 256, 0, stream>>>(src0, dst0, src1, dst1, rp, tmp, dinv, csw);
    cvt_x_bf16<<<cdiv_i(N0c * 32, 256), 256, 0, stream>>>(x, xbf);
    prep_weights<<<386, 256, 0, stream>>>(W_in0, W_h0, b0, g0, be0, m0, v0,
                                          Wt0, Wt1, sc0, sh0, sc1, sh1);

    const int*   rp1   = rp + N0c;
    const float* dinv1 = dinv + N0c;

    // ---- phase A: 3 GCN layers on N0 (layers 0/1: bf16 MFMA path) ----
    agg_bf16<16, 2, true><<<2 * cdiv_i(N0c, 4), 256, 0, stream>>>(xbf, rp, csw, dinv, z0bf, N0c);
    gemm_mfma_bn<128><<<cdiv_i(N0c, 64), 256, 0, stream>>>(z0bf, Wt0, sc0, sh0, g0bf, N0c);
    agg_bf16<32, 4, true><<<4 * cdiv_i(N0c, 4), 256, 0, stream>>>(g0bf, rp, csw, dinv, z1bf, N0c);
    gemm_mfma_bn<256><<<cdiv_i(N0c, 64), 256, 0, stream>>>(z1bf, Wt1, sc1, sh1, g1bf, N0c);
    agg_bf16<32, 4, false><<<4 * cdiv_i(N0c, 4), 256, 0, stream>>>(g1bf, rp, csw, dinv, bufA, N0c);

    // layer 2: pool BEFORE GEMM (affine reorder); fp32 vector GEMM (precision)
    seg_starts<<<cdiv_i(N0c + 1, 256), 256, 0, stream>>>(pool1, N0c, N1c, start0);
    pool_mean<<<N1c, 64, 0, stream>>>(bufA, start0, batch, pmean, cnt0, bpool);
    gemm_bn<256, false, true, false><<<dim3(cdiv_i(N1c, 64), 4), 256, 0, stream>>>(
        pmean, W_h0 + Hc * Hc, b0 + 2 * Hc, g0 + 2 * Hc, be0 + 2 * Hc, m0 + 2 * Hc,
        v0 + 2 * Hc, cnt0, xp, N1c);

    // head0: logits + softmax -> d_out[0:48000], xb = [x0 | x_pool1]
    head0<<<N1c, 64, 0, stream>>>(xp, linW0, linb0, x_pool1, outp, xb);

    // ---- phase B: 3 GCN layers on N1 (fp32 vector GEMMs) ----
    agg17_gemm_bn<<<N1c, 256, 0, stream>>>(xb, rp1, csw, dinv1, W_in1, b1, g1, be1,
                                           m1, v1, hbbbf);
    agg_bf16<32, 4, false><<<4 * cdiv_i(N1c, 4), 256, 0, stream>>>(hbbbf, rp1, csw, dinv1, zbb, N1c);
    gemm_bn<256, true, false, true><<<dim3(cdiv_i(N1c, 64), 4), 256, 0, stream>>>(
        zbb, W_h1, b1 + Hc, g1 + Hc, be1 + Hc, m1 + Hc, v1 + Hc, nullptr, hbbbf, N1c);
    agg_bf16<32, 4, false><<<4 * cdiv_i(N1c, 4), 256, 0, stream>>>(hbbbf, rp1, csw, dinv1, zbb, N1c);

    // layer 2: pool to B graphs BEFORE GEMM (bpool is NOT sorted -> atomics)
    pool_b_accum<<<N1c, 64, 0, stream>>>(zbb, bpool, pb, cntB);

    // head1: layer2 GEMM+BN + logits + softmax -> d_out[48000:48256]
    head1<<<Bc, 256, 0, stream>>>(pb, cntB, W_h1 + Hc * Hc, b1 + 2 * Hc, g1 + 2 * Hc,
                                  be1 + 2 * Hc, m1 + 2 * Hc, v1 + 2 * Hc, linW1, linb1,
                                  outp);
}